// Round 10
// baseline (1121.636 us; speedup 1.0000x reference)
//
#include <hip/hip_runtime.h>
#include <hip/hip_bf16.h>
#include <cstdio>
#include <cstdint>

#define BATCH 32
#define SEQ 512
#define BSQ (BATCH*SEQ)      // 16384
#define HIDD 300
#define HD 64
#define NHEAD 8
#define DHEAD 8
#define NLAYERS 6
#define FFD 1200
#define NCLS 1000
#define NSPLIT 2
#define KCH (SEQ/NSPLIT)     // 256 keys per block
#define QKVP 256             // bf16 qkv row stride (tile-rounded)
#define CLS_KS 4
#define CLS_KC (HIDD/CLS_KS) // 75

typedef short short8 __attribute__((ext_vector_type(8)));
typedef float floatx4 __attribute__((ext_vector_type(4)));

__device__ __forceinline__ short f2b(float v){
  __hip_bfloat16 h = __float2bfloat16(v);
  short s; __builtin_memcpy(&s, &h, 2); return s;
}
__device__ __forceinline__ unsigned pk2(float a, float b){
  return (unsigned)(unsigned short)f2b(a) | ((unsigned)(unsigned short)f2b(b) << 16);
}

// ------- embedding + positional encoding -> acc = 2*emb + pos (fp32 + bf16) -
__global__ void t10_embed(const int* __restrict__ toks,
                          const float* __restrict__ emb,
                          float* __restrict__ acc,
                          short* __restrict__ accbf){
  int idx = blockIdx.x*256 + threadIdx.x;
  if (idx >= BSQ*320) return;
  int row = idx / 320;
  int j   = idx - row*320;
  if (j >= HIDD){ accbf[(size_t)row*320 + j] = 0; return; }
  int t = toks[row];
  float e = emb[(size_t)t*HIDD + j];
  int s = row & (SEQ-1);
  float expo = (float)(j & ~1) * (1.0f/(float)HIDD);
  float ang  = (float)s * expf(-expo * 9.210340371976184f);
  float pe   = (j & 1) ? cosf(ang) : sinf(ang);
  float v = 2.0f*e + pe;
  acc[(size_t)row*HIDD + j] = v;
  accbf[(size_t)row*320 + j] = f2b(v);
}

// ------- weight prep: fp32 [K][N] -> bf16 transposed [Npad][Kpad] -----------
__global__ void prep_w(const float* __restrict__ src, short* __restrict__ dst,
                       int K, int N, int Kpad, int rows, int nbase,
                       int sls, int dls, int total, int perm, float smul){
  int idx = blockIdx.x*256 + threadIdx.x;
  if (idx >= total) return;
  int l   = idx / (rows*Kpad);
  int rem = idx - l*(rows*Kpad);
  int n = rem / Kpad;
  int k = rem - n*Kpad;
  int sc = perm ? ((n & 7)*8 + (n >> 3)) : n;
  float v = (n < N && k < K) ? src[(size_t)l*sls + (size_t)k*N + sc]*smul : 0.f;
  dst[(size_t)l*dls + (size_t)(nbase+n)*Kpad + k] = f2b(v);
}

// ---- bf16 MFMA GEMM, 64x64 tile; optional fp32 residual in epilogue (WO) ---
__global__ __launch_bounds__(256) void mm_a16(
    const short* __restrict__ A, const short* __restrict__ Wt,
    const float* __restrict__ bias, const float* __restrict__ resid,
    float* __restrict__ C, short* __restrict__ Cb,
    int M, int N, int Kpad, int Npad, int nnb, int relu){
  __shared__ short sA[64][40];
  __shared__ short sB[64][40];
  int wg = blockIdx.x;
  int cpx = gridDim.x >> 3;
  int swz = (wg & 7)*cpx + (wg >> 3);
  int mt = swz / nnb, nt = swz - mt*nnb;
  int m0 = mt*64, n0 = nt*64;
  int tid = threadIdx.x;
  int lane = tid & 63, wv = tid >> 6;
  int wm = (wv & 1)*32, wn = (wv >> 1)*32;
  int l15 = lane & 15, quad = lane >> 4;
  floatx4 acc[2][2] = {};
  int srow = tid >> 2, sko = (tid & 3)*8;
  const short* Arow = A  + (size_t)(m0 + srow)*Kpad + sko;
  const short* Brow = Wt + (size_t)(n0 + srow)*Kpad + sko;
  int nch = Kpad >> 5;
  for (int c = 0; c < nch; c++){
    int k0 = c*32;
    __syncthreads();
    *(short8*)&sA[srow][sko] = *(const short8*)(Arow + k0);
    *(short8*)&sB[srow][sko] = *(const short8*)(Brow + k0);
    __syncthreads();
    short8 af[2], bf[2];
    for (int i=0;i<2;i++)
      af[i] = *(const short8*)&sA[wm + i*16 + l15][quad*8];
    for (int j=0;j<2;j++)
      bf[j] = *(const short8*)&sB[wn + j*16 + l15][quad*8];
    for (int i=0;i<2;i++)
      for (int j=0;j<2;j++)
        acc[i][j] = __builtin_amdgcn_mfma_f32_16x16x32_bf16(af[i], bf[j], acc[i][j], 0,0,0);
  }
  if (Cb){
    for (int j=0;j<2;j++){
      int n = n0 + wn + j*16 + l15;
      float bv = (bias && n < N) ? bias[n] : 0.f;
      for (int i=0;i<2;i++){
        int mbase = m0 + wm + i*16 + quad*4;
        for (int r=0;r<4;r++){
          float cv = acc[i][j][r] + bv;
          if (relu) cv = fmaxf(cv, 0.f);
          Cb[(size_t)(mbase+r)*Npad + n] = (n < N) ? f2b(cv) : (short)0;
        }
      }
    }
  } else {
    for (int j=0;j<2;j++){
      int n = n0 + wn + j*16 + l15;
      if (n >= N) continue;
      float bv = bias ? bias[n] : 0.f;
      for (int i=0;i<2;i++){
        int mbase = m0 + wm + i*16 + quad*4;
        for (int r=0;r<4;r++){
          size_t ci = (size_t)(mbase+r)*N + n;
          float cv = acc[i][j][r] + bv;
          if (resid) cv += resid[ci];
          if (relu) cv = fmaxf(cv, 0.f);
          C[ci] = cv;
        }
      }
    }
  }
}

// ---- bf16 MFMA GEMM, 64x128 tile; optional fp32 residual (QKV / FF2) -------
__global__ __launch_bounds__(256) void mm64(
    const short* __restrict__ A, const short* __restrict__ Wt,
    const float* __restrict__ bias, const float* __restrict__ resid,
    float* __restrict__ C, short* __restrict__ Cb,
    int M, int N, int Kpad, int Npad, int nnb, int relu){
  __shared__ short sA[64][40];
  __shared__ short sB[128][40];
  int wg = blockIdx.x;
  int cpx = gridDim.x >> 3;
  int swz = (wg & 7)*cpx + (wg >> 3);
  int mt = swz / nnb, nt = swz - mt*nnb;
  int m0 = mt*64, n0 = nt*128;
  int tid = threadIdx.x;
  int lane = tid & 63, wv = tid >> 6;
  int l15 = lane & 15, quad = lane >> 4;
  int wn = wv*32;
  floatx4 acc[4][2] = {};
  int lr = tid >> 2, lc = (tid & 3)*8;
  const short* Arow  = A  + (size_t)(m0 + lr)*Kpad + lc;
  const short* Brow0 = Wt + (size_t)(n0 + lr)*Kpad + lc;
  const short* Brow1 = Wt + (size_t)(n0 + 64 + lr)*Kpad + lc;
  int nch = Kpad >> 5;
  for (int c = 0; c < nch; c++){
    int k0 = c*32;
    short8 va  = *(const short8*)(Arow  + k0);
    short8 vb0 = *(const short8*)(Brow0 + k0);
    short8 vb1 = *(const short8*)(Brow1 + k0);
    __syncthreads();
    *(short8*)&sA[lr][lc]      = va;
    *(short8*)&sB[lr][lc]      = vb0;
    *(short8*)&sB[64+lr][lc]   = vb1;
    __syncthreads();
    short8 af[4], bf[2];
    #pragma unroll
    for (int i=0;i<4;i++)
      af[i] = *(const short8*)&sA[i*16 + l15][quad*8];
    #pragma unroll
    for (int j=0;j<2;j++)
      bf[j] = *(const short8*)&sB[wn + j*16 + l15][quad*8];
    #pragma unroll
    for (int i=0;i<4;i++)
      #pragma unroll
      for (int j=0;j<2;j++)
        acc[i][j] = __builtin_amdgcn_mfma_f32_16x16x32_bf16(af[i], bf[j], acc[i][j], 0,0,0);
  }
  if (Cb){
    #pragma unroll
    for (int j=0;j<2;j++){
      int n = n0 + wn + j*16 + l15;
      float bv = (bias && n < N) ? bias[n] : 0.f;
      #pragma unroll
      for (int i=0;i<4;i++){
        int mbase = m0 + i*16 + quad*4;
        #pragma unroll
        for (int r=0;r<4;r++){
          float cv = acc[i][j][r] + bv;
          if (relu) cv = fmaxf(cv, 0.f);
          Cb[(size_t)(mbase+r)*Npad + n] = (n < N) ? f2b(cv) : (short)0;
        }
      }
    }
  } else {
    #pragma unroll
    for (int j=0;j<2;j++){
      int n = n0 + wn + j*16 + l15;
      if (n >= N) continue;
      float bv = bias ? bias[n] : 0.f;
      #pragma unroll
      for (int i=0;i<4;i++){
        int mbase = m0 + i*16 + quad*4;
        #pragma unroll
        for (int r=0;r<4;r++){
          size_t ci = (size_t)(mbase+r)*N + n;
          float cv = acc[i][j][r] + bv;
          if (resid) cv += resid[ci];
          if (relu) cv = fmaxf(cv, 0.f);
          C[ci] = cv;
        }
      }
    }
  }
}

// ---- bf16 MFMA GEMM, 128x128 tile, reg-staged, padded LDS (FF1) ------------
__global__ __launch_bounds__(256) void mm128p(
    const short* __restrict__ A, const short* __restrict__ Wt,
    const float* __restrict__ bias, float* __restrict__ C,
    short* __restrict__ Cb,
    int M, int N, int Kpad, int Npad, int nnb, int relu){
  __shared__ short sA[128][40];
  __shared__ short sB[128][40];
  int wg = blockIdx.x;
  int cpx = gridDim.x >> 3;
  int swz = (wg & 7)*cpx + (wg >> 3);
  int mt = swz / nnb, nt = swz - mt*nnb;
  int m0 = mt*128, n0 = nt*128;
  int tid = threadIdx.x;
  int lane = tid & 63, wv = tid >> 6;
  int wm = (wv & 1)*64, wn = (wv >> 1)*64;
  int l15 = lane & 15, quad = lane >> 4;
  floatx4 acc[4][4] = {};
  int lr = tid >> 2, lc = (tid & 3)*8;
  const short* Arow0 = A  + (size_t)(m0 + lr)*Kpad + lc;
  const short* Arow1 = A  + (size_t)(m0 + 64 + lr)*Kpad + lc;
  const short* Brow0 = Wt + (size_t)(n0 + lr)*Kpad + lc;
  const short* Brow1 = Wt + (size_t)(n0 + 64 + lr)*Kpad + lc;
  int nch = Kpad >> 5;
  for (int c = 0; c < nch; c++){
    int k0 = c*32;
    short8 va0 = *(const short8*)(Arow0 + k0);
    short8 va1 = *(const short8*)(Arow1 + k0);
    short8 vb0 = *(const short8*)(Brow0 + k0);
    short8 vb1 = *(const short8*)(Brow1 + k0);
    __syncthreads();
    *(short8*)&sA[lr][lc]    = va0;
    *(short8*)&sA[64+lr][lc] = va1;
    *(short8*)&sB[lr][lc]    = vb0;
    *(short8*)&sB[64+lr][lc] = vb1;
    __syncthreads();
    short8 af[4], bf[4];
    #pragma unroll
    for (int i=0;i<4;i++)
      af[i] = *(const short8*)&sA[wm + i*16 + l15][quad*8];
    #pragma unroll
    for (int j=0;j<4;j++)
      bf[j] = *(const short8*)&sB[wn + j*16 + l15][quad*8];
    #pragma unroll
    for (int i=0;i<4;i++)
      #pragma unroll
      for (int j=0;j<4;j++)
        acc[i][j] = __builtin_amdgcn_mfma_f32_16x16x32_bf16(af[i], bf[j], acc[i][j], 0,0,0);
  }
  if (Cb){
    #pragma unroll
    for (int j=0;j<4;j++){
      int n = n0 + wn + j*16 + l15;
      float bv = (bias && n < N) ? bias[n] : 0.f;
      #pragma unroll
      for (int i=0;i<4;i++){
        int mbase = m0 + wm + i*16 + quad*4;
        #pragma unroll
        for (int r=0;r<4;r++){
          float cv = acc[i][j][r] + bv;
          if (relu) cv = fmaxf(cv, 0.f);
          Cb[(size_t)(mbase+r)*Npad + n] = (n < N) ? f2b(cv) : (short)0;
        }
      }
    }
  } else {
    #pragma unroll
    for (int j=0;j<4;j++){
      int n = n0 + wn + j*16 + l15;
      if (n >= N) continue;
      float bv = bias ? bias[n] : 0.f;
      #pragma unroll
      for (int i=0;i<4;i++){
        int mbase = m0 + wm + i*16 + quad*4;
        #pragma unroll
        for (int r=0;r<4;r++){
          float cv = acc[i][j][r] + bv;
          if (relu) cv = fmaxf(cv, 0.f);
          C[(size_t)(mbase+r)*N + n] = cv;
        }
      }
    }
  }
}

// ---- MFMA attention partial, NSPLIT=2: 256 keys/block ----------------------
__global__ __launch_bounds__(256) void t19_attn(
    const short* __restrict__ qkvb, const int* __restrict__ toks,
    float* __restrict__ pp, float* __restrict__ ps){
  __shared__ short vb16[KCH][16];   // bf16 V rows
  __shared__ float msk[KCH];
  __shared__ short Pl[4][16][KCH+8];
  int blk = blockIdx.x;
  int ks = blk & (NSPLIT-1);
  int bh = blk >> 1;
  int b = bh >> 3, h = bh & 7;
  int tid = threadIdx.x;
  int lane = tid & 63, w = tid >> 6;
  int quad = lane >> 4, l15 = lane & 15;
  int kbase = ks*KCH;
  *(short8*)&vb16[tid][0] =
    *(const short8*)(qkvb + (size_t)(b*SEQ + kbase + tid)*QKVP + 128 + h*8);
  msk[tid] = (toks[b*SEQ + kbase + tid]==0) ? -1e9f : 0.f;
  __syncthreads();

  // K A-frags: direct from global (quad==0 lanes hold data)
  short8 kfrag[16];
  #pragma unroll
  for (int kt=0;kt<16;kt++){
    short8 f;
    #pragma unroll
    for (int j=0;j<8;j++) f[j] = 0;
    if (quad == 0)
      f = *(const short8*)(qkvb + (size_t)(b*SEQ + kbase + kt*16 + l15)*QKVP + 64 + h*8);
    kfrag[kt] = f;
  }
  // V^T B-frags from LDS; col 8 = ones -> sum(p)
  short8 vfrag[8];
  #pragma unroll
  for (int ks2=0;ks2<8;ks2++){
    short8 f;
    #pragma unroll
    for (int j=0;j<8;j++) f[j] = 0;
    if (l15 < 8){
      #pragma unroll
      for (int j=0;j<8;j++) f[j] = vb16[ks2*32 + quad*8 + j][l15];
    } else if (l15 == 8){
      #pragma unroll
      for (int j=0;j<8;j++) f[j] = (short)0x3F80;
    }
    vfrag[ks2] = f;
  }

  for (int t = 0; t < 8; t++){
    int q0 = w*128 + t*16;
    short8 qf;
    #pragma unroll
    for (int j=0;j<8;j++) qf[j] = 0;
    if (quad == 0)
      qf = *(const short8*)(qkvb + (size_t)(b*SEQ + q0 + l15)*QKVP + h*8);
    #pragma unroll
    for (int kt2 = 0; kt2 < 8; kt2++){
      floatx4 z = {0.f,0.f,0.f,0.f};
      floatx4 a0 = __builtin_amdgcn_mfma_f32_16x16x32_bf16(kfrag[2*kt2],   qf, z, 0,0,0);
      floatx4 a1 = __builtin_amdgcn_mfma_f32_16x16x32_bf16(kfrag[2*kt2+1], qf, z, 0,0,0);
      float p0[4], p1[4];
      #pragma unroll
      for (int r=0;r<4;r++){
        float m0 = msk[(2*kt2)*16   + quad*4 + r];
        float m1 = msk[(2*kt2+1)*16 + quad*4 + r];
        p0[r] = __expf(fminf(a0[r] + m0, 60.f));
        p1[r] = __expf(fminf(a1[r] + m1, 60.f));
      }
      uint2 u0, u1;
      u0.x = pk2(p0[0], p0[1]); u0.y = pk2(p0[2], p0[3]);
      u1.x = pk2(p1[0], p1[1]); u1.y = pk2(p1[2], p1[3]);
      *(uint2*)&Pl[w][l15][(2*kt2)*16   + quad*4] = u0;
      *(uint2*)&Pl[w][l15][(2*kt2+1)*16 + quad*4] = u1;
    }
    floatx4 o = {0.f,0.f,0.f,0.f};
    #pragma unroll
    for (int ks2=0; ks2<8; ks2++){
      short8 pa = *(const short8*)&Pl[w][l15][ks2*32 + quad*8];
      o = __builtin_amdgcn_mfma_f32_16x16x32_bf16(pa, vfrag[ks2], o, 0,0,0);
    }
    if (l15 < 8){
      #pragma unroll
      for (int r=0;r<4;r++){
        int q = q0 + quad*4 + r;
        pp[(size_t)ks*BSQ*64 + (size_t)(b*SEQ+q)*64 + h*8 + l15] = o[r];
      }
    } else if (l15 == 8){
      #pragma unroll
      for (int r=0;r<4;r++){
        int q = q0 + quad*4 + r;
        ps[(size_t)ks*BSQ*8 + (size_t)(b*SEQ+q)*8 + h] = o[r];
      }
    }
  }
}

// ---- attention combine: sum NSPLIT partials, normalize, emit bf16 ----------
__global__ __launch_bounds__(256) void t12_attn_comb(
    const float* __restrict__ pp, const float* __restrict__ ps,
    short* __restrict__ aout){
  int idx = blockIdx.x*256 + threadIdx.x;   // (bsq, h)
  if (idx >= BSQ*8) return;
  float s = 0.f;
  for (int k=0;k<NSPLIT;k++) s += ps[(size_t)k*BSQ*8 + idx];
  float inv = 1.f/s;
  int bsq = idx >> 3, h = idx & 7;
  size_t base = (size_t)bsq*64 + h*8;
  float o[8] = {};
  for (int k=0;k<NSPLIT;k++){
    const float4* p = (const float4*)(pp + (size_t)k*BSQ*64 + base);
    float4 a = p[0], bq = p[1];
    o[0]+=a.x; o[1]+=a.y; o[2]+=a.z; o[3]+=a.w;
    o[4]+=bq.x; o[5]+=bq.y; o[6]+=bq.z; o[7]+=bq.w;
  }
  short8 r;
  for (int d=0;d<8;d++) r[d] = f2b(o[d]*inv);
  *(short8*)(aout + base) = r;
}

// ---- LayerNorm (ddof=1), wave-per-row x4; xb optional (residual pre-fused) -
__global__ __launch_bounds__(256) void t19_addnorm(
                 const float* __restrict__ xa, const float* __restrict__ xb,
                 float* __restrict__ y, short* __restrict__ ybf,
                 float* __restrict__ accum, short* __restrict__ accbf,
                 const float* __restrict__ gamma, const float* __restrict__ beta,
                 int l){
  int w = threadIdx.x >> 6, lane = threadIdx.x & 63;
  int row = blockIdx.x*4 + w;
  size_t base  = (size_t)row*HIDD;
  size_t bbase = (size_t)row*320;
  float v[5];
  float s = 0.f, sq = 0.f;
  #pragma unroll
  for (int t=0;t<5;t++){
    int j = lane + t*64;
    float x = 0.f;
    if (j < HIDD){
      x = xa[base+j];
      if (xb) x += xb[base+j];
    }
    v[t] = x; s += x; sq += x*x;
  }
  #pragma unroll
  for (int off=32; off; off>>=1){ s += __shfl_down(s,off); sq += __shfl_down(sq,off); }
  s = __shfl(s, 0); sq = __shfl(sq, 0);
  float mu  = s * (1.0f/HIDD);
  float var = (sq - (float)HIDD*mu*mu) * (1.0f/(HIDD-1));
  float rstd = rsqrtf(var + 1e-8f);
  float g = gamma[l], be = beta[l];
  #pragma unroll
  for (int t=0;t<5;t++){
    int j = lane + t*64;
    if (j < HIDD){
      float o = g*(v[t]-mu)*rstd + be;
      if (y) y[base+j] = o;
      if (ybf) ybf[bbase+j] = f2b(o);
      if (accum){
        float a = accum[base+j] + o;
        accum[base+j] = a;
        if (accbf) accbf[bbase+j] = f2b(a);
      }
    } else if (j < 320){
      if (ybf) ybf[bbase+j] = 0;
      if (accbf) accbf[bbase+j] = 0;
    }
  }
}

// ---- colsum stage 1: block = (b, seq-chunk of 64); sum 64 rows ------------
__global__ __launch_bounds__(256) void t13_colsum_part(
    const float* __restrict__ outb, float* __restrict__ part){
  int blk = blockIdx.x;            // 256 blocks: b*8 + c
  int b = blk >> 3, c = blk & 7;
  int tid = threadIdx.x;
  size_t base = (size_t)b*SEQ*HIDD + (size_t)c*64*HIDD;
  int j1 = tid + 256;
  float s0 = 0.f, s1 = 0.f;
  for (int t = 0; t < 64; t++){
    const float* row = outb + base + (size_t)t*HIDD;
    s0 += row[tid];
    if (j1 < HIDD) s1 += row[j1];
  }
  float* dst = part + (size_t)(c*BATCH + b)*HIDD;
  dst[tid] = s0;
  if (j1 < HIDD) dst[j1] = s1;
}

// ---- colsum stage 2: fold 8 partials -> sums[32][300] ----------------------
__global__ void t13_colsum_comb(const float* __restrict__ part,
                                float* __restrict__ sums){
  int idx = blockIdx.x*256 + threadIdx.x;   // b*300 + j
  if (idx >= BATCH*HIDD) return;
  float s = 0.f;
  for (int c = 0; c < 8; c++) s += part[(size_t)c*BATCH*HIDD + idx];
  sums[idx] = s;
}

// ---- classifier GEMM, split-K=4 --------------------------------------------
__global__ __launch_bounds__(256) void t13_cls(
    const float* __restrict__ sums, const float* __restrict__ W,
    float* __restrict__ plog){
  int gid = blockIdx.x*256 + threadIdx.x;
  if (gid >= CLS_KS*BATCH*NCLS) return;
  int c = gid / (BATCH*NCLS);
  int rem = gid - c*(BATCH*NCLS);
  int m = rem / NCLS, n = rem - m*NCLS;
  const float* arow = sums + m*HIDD + c*CLS_KC;
  const float* wcol = W + (size_t)c*CLS_KC*NCLS + n;
  float acc = 0.f;
  #pragma unroll 5
  for (int k = 0; k < CLS_KC; k++)
    acc = fmaf(arow[k], wcol[(size_t)k*NCLS], acc);
  plog[gid] = acc;
}

// ---------------- classifier head: LayerNorm(ddof=1) + softmax -> fp32 -----
__device__ __forceinline__ float t10_bsum(float val, float* red){
  for (int off=32; off; off>>=1) val += __shfl_down(val, off);
  __syncthreads();
  if ((threadIdx.x & 63)==0) red[threadIdx.x>>6] = val;
  __syncthreads();
  return red[0]+red[1]+red[2]+red[3];
}
__device__ __forceinline__ float t10_bmax(float val, float* red){
  for (int off=32; off; off>>=1) val = fmaxf(val, __shfl_down(val, off));
  __syncthreads();
  if ((threadIdx.x & 63)==0) red[threadIdx.x>>6] = val;
  __syncthreads();
  return fmaxf(fmaxf(red[0],red[1]), fmaxf(red[2],red[3]));
}

__global__ __launch_bounds__(256) void t10_final(
                  const float* __restrict__ plog,
                  const float* __restrict__ gf, const float* __restrict__ bff,
                  float* __restrict__ outp){
  __shared__ float red[4];
  int b = blockIdx.x, tid = threadIdx.x;
  size_t base = (size_t)b*NCLS;
  float v[4];
  float s = 0.f, sq = 0.f;
  for (int t=0;t<4;t++){
    int j = tid + t*256;
    float x = 0.f;
    if (j < NCLS){
      for (int c=0;c<CLS_KS;c++) x += plog[(size_t)c*BATCH*NCLS + base + j];
    }
    v[t] = x; s += x; sq += x*x;
  }
  s  = t10_bsum(s, red);
  sq = t10_bsum(sq, red);
  float mu  = s * (1.0f/NCLS);
  float var = (sq - (float)NCLS*mu*mu) * (1.0f/(NCLS-1));
  float rstd = rsqrtf(var + 1e-8f);
  float g = gf[0], be = bff[0];
  float y[4]; float mx = -1e30f;
  for (int t=0;t<4;t++){
    int j = tid + t*256;
    y[t] = g*(v[t]-mu)*rstd + be;
    if (j < NCLS) mx = fmaxf(mx, y[t]);
  }
  mx = t10_bmax(mx, red);
  float p[4]; float es = 0.f;
  for (int t=0;t<4;t++){
    int j = tid + t*256;
    p[t] = (j < NCLS) ? __expf(y[t]-mx) : 0.f;
    es += p[t];
  }
  es = t10_bsum(es, red);
  float inv = 1.0f/es;
  for (int t=0;t<4;t++){
    int j = tid + t*256;
    if (j < NCLS) outp[base+j] = p[t]*inv;
  }
}

// ---------------------------------------------------------------------------
extern "C" void kernel_launch(void* const* d_in, const int* in_sizes, int n_in,
                              void* d_out, int out_size, void* d_ws, size_t ws_size,
                              hipStream_t stream){
  const int*   toks = (const int*)d_in[0];
  const float* emb  = (const float*)d_in[1];
  const float* WQ   = (const float*)d_in[2];
  const float* WK   = (const float*)d_in[3];
  const float* WV   = (const float*)d_in[4];
  const float* WO   = (const float*)d_in[5];
  const float* W1   = (const float*)d_in[6];
  const float* b1   = (const float*)d_in[7];
  const float* W2   = (const float*)d_in[8];
  const float* b2   = (const float*)d_in[9];
  const float* g1   = (const float*)d_in[10];
  const float* be1  = (const float*)d_in[11];
  const float* g2   = (const float*)d_in[12];
  const float* be2  = (const float*)d_in[13];
  const float* Vd   = (const float*)d_in[14];
  const float* gf   = (const float*)d_in[15];
  const float* bff  = (const float*)d_in[16];
  float* outp = (float*)d_out;

  // fp32 buffers
  float* acc    = (float*)d_ws;                         // [BSQ][300]
  float* xn     = acc    + (size_t)BSQ*HIDD;            // [BSQ][300]
  float* outb   = xn     + (size_t)BSQ*HIDD;            // [BSQ][300]
  float* tmp    = outb   + (size_t)BSQ*HIDD;            // [BSQ][300]
  float* qkv    = tmp    + (size_t)BSQ*HIDD;            // slot: >= BSQ*QKVP bf16
  float* sums   = qkv    + (size_t)BSQ*192;             // [32][300]
  float* logits = sums   + BATCH*HIDD;                  // [32][1000] (pad)
  short* qkv_bf = (short*)qkv;                          // [BSQ][QKVP] bf16
  // attention partials alias tmp (dead during attention)
  float* pp     = tmp;
  float* ps     = tmp + (size_t)NSPLIT*BSQ*64;
  // bf16 buffers
  short* acc_bf = (short*)(logits + BATCH*NCLS);        // [BSQ][320]
  short* xn_bf  = acc_bf + (size_t)BSQ*320;             // [BSQ][320]
  short* aat_bf = xn_bf  + (size_t)BSQ*320;             // [BSQ][64]
  short* ff1_bf = aat_bf + (size_t)BSQ*64;              // [BSQ][1280]
  // bf16 weights (row counts padded to 128-tile multiples)
  short* wqkv = ff1_bf + (size_t)BSQ*1280;              // [6][256][320]
  short* wo   = wqkv + (size_t)6*256*320;               // [6][384][64]
  short* w1t  = wo   + (size_t)6*384*64;                // [6][1280][320]
  short* w2t  = w1t  + (size_t)6*1280*320;              // [6][384][1280]
  // classifier-tail fp32 buffers
  float* cspart = (float*)(w2t + (size_t)6*384*1280);   // [8][32][300]
  float* plog   = cspart + (size_t)8*BATCH*HIDD;        // [4][32][1000]

  {
    const float kscale = 0.057735026918962574f;         // 1/sqrt(300) into WK
    int tq = 6*64*320;
    prep_w<<<(tq+255)/256,256,0,stream>>>(WQ, wqkv, 300, 64, 320, 64, 0,   19200, 81920, tq, 1, 1.0f);
    prep_w<<<(tq+255)/256,256,0,stream>>>(WK, wqkv, 300, 64, 320, 64, 64,  19200, 81920, tq, 1, kscale);
    prep_w<<<(tq+255)/256,256,0,stream>>>(WV, wqkv, 300, 64, 320, 64, 128, 19200, 81920, tq, 1, 1.0f);
    prep_w<<<(tq+255)/256,256,0,stream>>>(WQ, wqkv, 300, 0,  320, 64, 192, 19200, 81920, tq, 0, 1.0f);
    int to = 6*384*64;
    prep_w<<<(to+255)/256,256,0,stream>>>(WO, wo, 64, 300, 64, 384, 0, 19200, 24576, to, 0, 1.0f);
    int t1 = 6*1280*320;
    prep_w<<<(t1+255)/256,256,0,stream>>>(W1, w1t, 300, 1200, 320, 1280, 0, 360000, 409600, t1, 0, 1.0f);
    int t2 = 6*384*1280;
    prep_w<<<(t2+255)/256,256,0,stream>>>(W2, w2t, 1200, 300, 1280, 384, 0, 360000, 491520, t2, 0, 1.0f);
  }

  t10_embed<<<(BSQ*320+255)/256, 256, 0, stream>>>(toks, emb, acc, acc_bf);

  for (int l = 0; l < NLAYERS; l++){
    // QKV: [BSQ][320]bf16 @ [256][320] -> qkv_bf [BSQ][256] bf16 (scale in WK)
    mm64<<<256*2,256,0,stream>>>(acc_bf, wqkv + (size_t)l*81920, nullptr, nullptr,
                                 nullptr, qkv_bf, BSQ, 192, 320, QKVP, 2, 0);
    t19_attn<<<BATCH*NHEAD*NSPLIT, 256, 0, stream>>>(qkv_bf, toks, pp, ps);
    t12_attn_comb<<<(BSQ*8)/256, 256, 0, stream>>>(pp, ps, aat_bf);
    // WO + residual: tmp = aat @ WO + acc
    mm_a16<<<256*5,256,0,stream>>>(aat_bf, wo + (size_t)l*24576, nullptr, acc,
                                   tmp, nullptr, BSQ, 300, 64, 0, 5, 0);
    t19_addnorm<<<BSQ/4,256,0,stream>>>(tmp, nullptr, xn, xn_bf, nullptr, nullptr, g1, be1, l);
    // FF1: [BSQ][320]bf16 @ [1280][320] -> ff1 bf16 [BSQ][1280]
    mm128p<<<128*10,256,0,stream>>>(xn_bf, w1t + (size_t)l*409600, b1 + (size_t)l*FFD,
                                    nullptr, ff1_bf, BSQ, 1200, 320, 1280, 10, 1);
    // FF2 + residual: tmp = ff1 @ W2 + b2 + xn
    mm64<<<256*3,256,0,stream>>>(ff1_bf, w2t + (size_t)l*491520, b2 + (size_t)l*HIDD, xn,
                                 tmp, nullptr, BSQ, 300, 1280, 0, 3, 0);
    // l<5: outb write dead; l==5: acc accumulate dead
    t19_addnorm<<<BSQ/4,256,0,stream>>>(tmp, nullptr, (l==NLAYERS-1)?outb:nullptr, nullptr,
                                        (l==NLAYERS-1)?nullptr:acc,
                                        (l==NLAYERS-1)?nullptr:acc_bf, g2, be2, l);
  }

  t13_colsum_part<<<BATCH*8, 256, 0, stream>>>(outb, cspart);
  t13_colsum_comb<<<(BATCH*HIDD+255)/256, 256, 0, stream>>>(cspart, sums);
  t13_cls<<<(CLS_KS*BATCH*NCLS)/256, 256, 0, stream>>>(sums, Vd, plog);
  t10_final<<<BATCH, 256, 0, stream>>>(plog, gf, bff, outp);

  hipStreamCaptureStatus cs = hipStreamCaptureStatusNone;
  hipStreamIsCapturing(stream, &cs);
  if (cs == hipStreamCaptureStatusNone){
    hipError_t e_sync = hipStreamSynchronize(stream);
    float ho[4] = {-1,-1,-1,-1};
    hipMemcpy(ho, d_out, 16, hipMemcpyDeviceToHost);
    fprintf(stderr, "[t19] sync=%s out[0..3]=%g,%g,%g,%g\n",
            hipGetErrorString(e_sync), ho[0], ho[1], ho[2], ho[3]);
    fflush(stderr);
  }
}

// Round 11
// 1106.559 us; speedup vs baseline: 1.0136x; 1.0136x over previous
//
#include <hip/hip_runtime.h>
#include <hip/hip_bf16.h>
#include <cstdio>
#include <cstdint>

#define BATCH 32
#define SEQ 512
#define BSQ (BATCH*SEQ)      // 16384
#define HIDD 300
#define HD 64
#define NHEAD 8
#define DHEAD 8
#define NLAYERS 6
#define FFD 1200
#define NCLS 1000
#define NSPLIT 4
#define KCH (SEQ/NSPLIT)     // 128 keys per block
#define QKVP 256             // bf16 qkv row stride (tile-rounded)
#define CLS_KS 4
#define CLS_KC (HIDD/CLS_KS) // 75

typedef short short8 __attribute__((ext_vector_type(8)));
typedef float floatx4 __attribute__((ext_vector_type(4)));

__device__ __forceinline__ short f2b(float v){
  __hip_bfloat16 h = __float2bfloat16(v);
  short s; __builtin_memcpy(&s, &h, 2); return s;
}
__device__ __forceinline__ unsigned pk2(float a, float b){
  return (unsigned)(unsigned short)f2b(a) | ((unsigned)(unsigned short)f2b(b) << 16);
}

// ------- embedding + positional encoding -> acc = 2*emb + pos (fp32 + bf16) -
__global__ void t10_embed(const int* __restrict__ toks,
                          const float* __restrict__ emb,
                          float* __restrict__ acc,
                          short* __restrict__ accbf){
  int idx = blockIdx.x*256 + threadIdx.x;
  if (idx >= BSQ*320) return;
  int row = idx / 320;
  int j   = idx - row*320;
  if (j >= HIDD){ accbf[(size_t)row*320 + j] = 0; return; }
  int t = toks[row];
  float e = emb[(size_t)t*HIDD + j];
  int s = row & (SEQ-1);
  float expo = (float)(j & ~1) * (1.0f/(float)HIDD);
  float ang  = (float)s * expf(-expo * 9.210340371976184f);
  float pe   = (j & 1) ? cosf(ang) : sinf(ang);
  float v = 2.0f*e + pe;
  acc[(size_t)row*HIDD + j] = v;
  accbf[(size_t)row*320 + j] = f2b(v);
}

// ------- weight prep: fp32 [K][N] -> bf16 transposed [Npad][Kpad] -----------
__global__ void prep_w(const float* __restrict__ src, short* __restrict__ dst,
                       int K, int N, int Kpad, int rows, int nbase,
                       int sls, int dls, int total, int perm, float smul){
  int idx = blockIdx.x*256 + threadIdx.x;
  if (idx >= total) return;
  int l   = idx / (rows*Kpad);
  int rem = idx - l*(rows*Kpad);
  int n = rem / Kpad;
  int k = rem - n*Kpad;
  int sc = perm ? ((n & 7)*8 + (n >> 3)) : n;
  float v = (n < N && k < K) ? src[(size_t)l*sls + (size_t)k*N + sc]*smul : 0.f;
  dst[(size_t)l*dls + (size_t)(nbase+n)*Kpad + k] = f2b(v);
}

// ---- bf16 MFMA GEMM, 64x64 tile (WO) ---------------------------------------
__global__ __launch_bounds__(256) void mm_a16(
    const short* __restrict__ A, const short* __restrict__ Wt,
    const float* __restrict__ bias, float* __restrict__ C,
    short* __restrict__ Cb,
    int M, int N, int Kpad, int Npad, int nnb, int relu){
  __shared__ short sA[64][40];
  __shared__ short sB[64][40];
  int wg = blockIdx.x;
  int cpx = gridDim.x >> 3;
  int swz = (wg & 7)*cpx + (wg >> 3);
  int mt = swz / nnb, nt = swz - mt*nnb;
  int m0 = mt*64, n0 = nt*64;
  int tid = threadIdx.x;
  int lane = tid & 63, wv = tid >> 6;
  int wm = (wv & 1)*32, wn = (wv >> 1)*32;
  int l15 = lane & 15, quad = lane >> 4;
  floatx4 acc[2][2] = {};
  int srow = tid >> 2, sko = (tid & 3)*8;
  const short* Arow = A  + (size_t)(m0 + srow)*Kpad + sko;
  const short* Brow = Wt + (size_t)(n0 + srow)*Kpad + sko;
  int nch = Kpad >> 5;
  for (int c = 0; c < nch; c++){
    int k0 = c*32;
    __syncthreads();
    *(short8*)&sA[srow][sko] = *(const short8*)(Arow + k0);
    *(short8*)&sB[srow][sko] = *(const short8*)(Brow + k0);
    __syncthreads();
    short8 af[2], bf[2];
    for (int i=0;i<2;i++)
      af[i] = *(const short8*)&sA[wm + i*16 + l15][quad*8];
    for (int j=0;j<2;j++)
      bf[j] = *(const short8*)&sB[wn + j*16 + l15][quad*8];
    for (int i=0;i<2;i++)
      for (int j=0;j<2;j++)
        acc[i][j] = __builtin_amdgcn_mfma_f32_16x16x32_bf16(af[i], bf[j], acc[i][j], 0,0,0);
  }
  if (Cb){
    for (int j=0;j<2;j++){
      int n = n0 + wn + j*16 + l15;
      float bv = (bias && n < N) ? bias[n] : 0.f;
      for (int i=0;i<2;i++){
        int mbase = m0 + wm + i*16 + quad*4;
        for (int r=0;r<4;r++){
          float cv = acc[i][j][r] + bv;
          if (relu) cv = fmaxf(cv, 0.f);
          Cb[(size_t)(mbase+r)*Npad + n] = (n < N) ? f2b(cv) : (short)0;
        }
      }
    }
  } else {
    for (int j=0;j<2;j++){
      int n = n0 + wn + j*16 + l15;
      if (n >= N) continue;
      float bv = bias ? bias[n] : 0.f;
      for (int i=0;i<2;i++){
        int mbase = m0 + wm + i*16 + quad*4;
        for (int r=0;r<4;r++){
          float cv = acc[i][j][r] + bv;
          if (relu) cv = fmaxf(cv, 0.f);
          C[(size_t)(mbase+r)*N + n] = cv;
        }
      }
    }
  }
}

// ---- bf16 MFMA GEMM, 64x128 tile, reg-staged, padded LDS (QKV) -------------
__global__ __launch_bounds__(256) void mm64(
    const short* __restrict__ A, const short* __restrict__ Wt,
    const float* __restrict__ bias, float* __restrict__ C,
    short* __restrict__ Cb,
    int M, int N, int Kpad, int Npad, int nnb, int relu){
  __shared__ short sA[64][40];
  __shared__ short sB[128][40];
  int wg = blockIdx.x;
  int cpx = gridDim.x >> 3;
  int swz = (wg & 7)*cpx + (wg >> 3);
  int mt = swz / nnb, nt = swz - mt*nnb;
  int m0 = mt*64, n0 = nt*128;
  int tid = threadIdx.x;
  int lane = tid & 63, wv = tid >> 6;
  int l15 = lane & 15, quad = lane >> 4;
  int wn = wv*32;
  floatx4 acc[4][2] = {};
  int lr = tid >> 2, lc = (tid & 3)*8;
  const short* Arow  = A  + (size_t)(m0 + lr)*Kpad + lc;
  const short* Brow0 = Wt + (size_t)(n0 + lr)*Kpad + lc;
  const short* Brow1 = Wt + (size_t)(n0 + 64 + lr)*Kpad + lc;
  int nch = Kpad >> 5;
  for (int c = 0; c < nch; c++){
    int k0 = c*32;
    short8 va  = *(const short8*)(Arow  + k0);
    short8 vb0 = *(const short8*)(Brow0 + k0);
    short8 vb1 = *(const short8*)(Brow1 + k0);
    __syncthreads();
    *(short8*)&sA[lr][lc]      = va;
    *(short8*)&sB[lr][lc]      = vb0;
    *(short8*)&sB[64+lr][lc]   = vb1;
    __syncthreads();
    short8 af[4], bf[2];
    #pragma unroll
    for (int i=0;i<4;i++)
      af[i] = *(const short8*)&sA[i*16 + l15][quad*8];
    #pragma unroll
    for (int j=0;j<2;j++)
      bf[j] = *(const short8*)&sB[wn + j*16 + l15][quad*8];
    #pragma unroll
    for (int i=0;i<4;i++)
      #pragma unroll
      for (int j=0;j<2;j++)
        acc[i][j] = __builtin_amdgcn_mfma_f32_16x16x32_bf16(af[i], bf[j], acc[i][j], 0,0,0);
  }
  if (Cb){
    #pragma unroll
    for (int j=0;j<2;j++){
      int n = n0 + wn + j*16 + l15;
      float bv = (bias && n < N) ? bias[n] : 0.f;
      #pragma unroll
      for (int i=0;i<4;i++){
        int mbase = m0 + i*16 + quad*4;
        #pragma unroll
        for (int r=0;r<4;r++){
          float cv = acc[i][j][r] + bv;
          if (relu) cv = fmaxf(cv, 0.f);
          Cb[(size_t)(mbase+r)*Npad + n] = (n < N) ? f2b(cv) : (short)0;
        }
      }
    }
  } else {
    #pragma unroll
    for (int j=0;j<2;j++){
      int n = n0 + wn + j*16 + l15;
      if (n >= N) continue;
      float bv = bias ? bias[n] : 0.f;
      #pragma unroll
      for (int i=0;i<4;i++){
        int mbase = m0 + i*16 + quad*4;
        #pragma unroll
        for (int r=0;r<4;r++){
          float cv = acc[i][j][r] + bv;
          if (relu) cv = fmaxf(cv, 0.f);
          C[(size_t)(mbase+r)*N + n] = cv;
        }
      }
    }
  }
}

// ---- bf16 MFMA GEMM, 64x128 tile, SPLIT-K=2 (FF2) --------------------------
// grid = 2*mtiles*nnb; slice ksl covers K-range [ksl*klen, (ksl+1)*klen).
// slice0 -> C0 (+bias); slice1 -> C1 (no bias).  Combine in addnorm.
__global__ __launch_bounds__(256) void mm64k(
    const short* __restrict__ A, const short* __restrict__ Wt,
    const float* __restrict__ bias, float* __restrict__ C0,
    float* __restrict__ C1,
    int M, int N, int ldK, int klen, int nnb){
  __shared__ short sA[64][40];
  __shared__ short sB[128][40];
  int wg = blockIdx.x;
  int cpx = gridDim.x >> 3;
  int swz = (wg & 7)*cpx + (wg >> 3);
  int ksl = swz & 1;
  int t2  = swz >> 1;
  int mt = t2 / nnb, nt = t2 - mt*nnb;
  int m0 = mt*64, n0 = nt*128;
  int koff = ksl*klen;
  int tid = threadIdx.x;
  int lane = tid & 63, wv = tid >> 6;
  int l15 = lane & 15, quad = lane >> 4;
  int wn = wv*32;
  floatx4 acc[4][2] = {};
  int lr = tid >> 2, lc = (tid & 3)*8;
  const short* Arow  = A  + (size_t)(m0 + lr)*ldK + koff + lc;
  const short* Brow0 = Wt + (size_t)(n0 + lr)*ldK + koff + lc;
  const short* Brow1 = Wt + (size_t)(n0 + 64 + lr)*ldK + koff + lc;
  int nch = klen >> 5;
  for (int c = 0; c < nch; c++){
    int k0 = c*32;
    short8 va  = *(const short8*)(Arow  + k0);
    short8 vb0 = *(const short8*)(Brow0 + k0);
    short8 vb1 = *(const short8*)(Brow1 + k0);
    __syncthreads();
    *(short8*)&sA[lr][lc]      = va;
    *(short8*)&sB[lr][lc]      = vb0;
    *(short8*)&sB[64+lr][lc]   = vb1;
    __syncthreads();
    short8 af[4], bf[2];
    #pragma unroll
    for (int i=0;i<4;i++)
      af[i] = *(const short8*)&sA[i*16 + l15][quad*8];
    #pragma unroll
    for (int j=0;j<2;j++)
      bf[j] = *(const short8*)&sB[wn + j*16 + l15][quad*8];
    #pragma unroll
    for (int i=0;i<4;i++)
      #pragma unroll
      for (int j=0;j<2;j++)
        acc[i][j] = __builtin_amdgcn_mfma_f32_16x16x32_bf16(af[i], bf[j], acc[i][j], 0,0,0);
  }
  float* C = ksl ? C1 : C0;
  const float* bs = ksl ? nullptr : bias;
  #pragma unroll
  for (int j=0;j<2;j++){
    int n = n0 + wn + j*16 + l15;
    if (n >= N) continue;
    float bv = bs ? bs[n] : 0.f;
    #pragma unroll
    for (int i=0;i<4;i++){
      int mbase = m0 + i*16 + quad*4;
      #pragma unroll
      for (int r=0;r<4;r++)
        C[(size_t)(mbase+r)*N + n] = acc[i][j][r] + bv;
    }
  }
}

// ---- bf16 MFMA GEMM, 128x128 tile, reg-staged, padded LDS (FF1) ------------
__global__ __launch_bounds__(256) void mm128p(
    const short* __restrict__ A, const short* __restrict__ Wt,
    const float* __restrict__ bias, float* __restrict__ C,
    short* __restrict__ Cb,
    int M, int N, int Kpad, int Npad, int nnb, int relu){
  __shared__ short sA[128][40];
  __shared__ short sB[128][40];
  int wg = blockIdx.x;
  int cpx = gridDim.x >> 3;
  int swz = (wg & 7)*cpx + (wg >> 3);
  int mt = swz / nnb, nt = swz - mt*nnb;
  int m0 = mt*128, n0 = nt*128;
  int tid = threadIdx.x;
  int lane = tid & 63, wv = tid >> 6;
  int wm = (wv & 1)*64, wn = (wv >> 1)*64;
  int l15 = lane & 15, quad = lane >> 4;
  floatx4 acc[4][4] = {};
  int lr = tid >> 2, lc = (tid & 3)*8;
  const short* Arow0 = A  + (size_t)(m0 + lr)*Kpad + lc;
  const short* Arow1 = A  + (size_t)(m0 + 64 + lr)*Kpad + lc;
  const short* Brow0 = Wt + (size_t)(n0 + lr)*Kpad + lc;
  const short* Brow1 = Wt + (size_t)(n0 + 64 + lr)*Kpad + lc;
  int nch = Kpad >> 5;
  for (int c = 0; c < nch; c++){
    int k0 = c*32;
    short8 va0 = *(const short8*)(Arow0 + k0);
    short8 va1 = *(const short8*)(Arow1 + k0);
    short8 vb0 = *(const short8*)(Brow0 + k0);
    short8 vb1 = *(const short8*)(Brow1 + k0);
    __syncthreads();
    *(short8*)&sA[lr][lc]    = va0;
    *(short8*)&sA[64+lr][lc] = va1;
    *(short8*)&sB[lr][lc]    = vb0;
    *(short8*)&sB[64+lr][lc] = vb1;
    __syncthreads();
    short8 af[4], bf[4];
    #pragma unroll
    for (int i=0;i<4;i++)
      af[i] = *(const short8*)&sA[wm + i*16 + l15][quad*8];
    #pragma unroll
    for (int j=0;j<4;j++)
      bf[j] = *(const short8*)&sB[wn + j*16 + l15][quad*8];
    #pragma unroll
    for (int i=0;i<4;i++)
      #pragma unroll
      for (int j=0;j<4;j++)
        acc[i][j] = __builtin_amdgcn_mfma_f32_16x16x32_bf16(af[i], bf[j], acc[i][j], 0,0,0);
  }
  if (Cb){
    #pragma unroll
    for (int j=0;j<4;j++){
      int n = n0 + wn + j*16 + l15;
      float bv = (bias && n < N) ? bias[n] : 0.f;
      #pragma unroll
      for (int i=0;i<4;i++){
        int mbase = m0 + wm + i*16 + quad*4;
        #pragma unroll
        for (int r=0;r<4;r++){
          float cv = acc[i][j][r] + bv;
          if (relu) cv = fmaxf(cv, 0.f);
          Cb[(size_t)(mbase+r)*Npad + n] = (n < N) ? f2b(cv) : (short)0;
        }
      }
    }
  } else {
    #pragma unroll
    for (int j=0;j<4;j++){
      int n = n0 + wn + j*16 + l15;
      if (n >= N) continue;
      float bv = bias ? bias[n] : 0.f;
      #pragma unroll
      for (int i=0;i<4;i++){
        int mbase = m0 + wm + i*16 + quad*4;
        #pragma unroll
        for (int r=0;r<4;r++){
          float cv = acc[i][j][r] + bv;
          if (relu) cv = fmaxf(cv, 0.f);
          C[(size_t)(mbase+r)*N + n] = cv;
        }
      }
    }
  }
}

// ---- MFMA attention partial: qkv bf16 [BSQ][QKVP]; scale pre-folded --------
__global__ __launch_bounds__(256) void t18_attn(
    const short* __restrict__ qkvb, const int* __restrict__ toks,
    float* __restrict__ pp, float* __restrict__ ps){
  __shared__ short vb16[KCH][16];
  __shared__ float msk[KCH];
  __shared__ short Pl[4][16][136];
  int blk = blockIdx.x;
  int ks = blk & (NSPLIT-1);
  int bh = blk >> 2;
  int b = bh >> 3, h = bh & 7;
  int tid = threadIdx.x;
  int lane = tid & 63, w = tid >> 6;
  int quad = lane >> 4, l15 = lane & 15;
  int kbase = ks*KCH;
  if (tid < KCH){
    *(short8*)&vb16[tid][0] =
      *(const short8*)(qkvb + (size_t)(b*SEQ + kbase + tid)*QKVP + 128 + h*8);
  } else {
    int r = tid - KCH;
    msk[r] = (toks[b*SEQ + kbase + r]==0) ? -1e9f : 0.f;
  }
  __syncthreads();

  short8 kfrag[8];
  #pragma unroll
  for (int kt=0;kt<8;kt++){
    short8 f;
    #pragma unroll
    for (int j=0;j<8;j++) f[j] = 0;
    if (quad == 0)
      f = *(const short8*)(qkvb + (size_t)(b*SEQ + kbase + kt*16 + l15)*QKVP + 64 + h*8);
    kfrag[kt] = f;
  }
  short8 vfrag[4];
  #pragma unroll
  for (int ks2=0;ks2<4;ks2++){
    short8 f;
    #pragma unroll
    for (int j=0;j<8;j++) f[j] = 0;
    if (l15 < 8){
      #pragma unroll
      for (int j=0;j<8;j++) f[j] = vb16[ks2*32 + quad*8 + j][l15];
    } else if (l15 == 8){
      #pragma unroll
      for (int j=0;j<8;j++) f[j] = (short)0x3F80;
    }
    vfrag[ks2] = f;
  }

  for (int t = 0; t < 8; t++){
    int q0 = w*128 + t*16;
    short8 qf;
    #pragma unroll
    for (int j=0;j<8;j++) qf[j] = 0;
    if (quad == 0)
      qf = *(const short8*)(qkvb + (size_t)(b*SEQ + q0 + l15)*QKVP + h*8);
    #pragma unroll
    for (int kt2 = 0; kt2 < 4; kt2++){
      floatx4 z = {0.f,0.f,0.f,0.f};
      floatx4 a0 = __builtin_amdgcn_mfma_f32_16x16x32_bf16(kfrag[2*kt2],   qf, z, 0,0,0);
      floatx4 a1 = __builtin_amdgcn_mfma_f32_16x16x32_bf16(kfrag[2*kt2+1], qf, z, 0,0,0);
      float p0[4], p1[4];
      #pragma unroll
      for (int r=0;r<4;r++){
        float m0 = msk[(2*kt2)*16   + quad*4 + r];
        float m1 = msk[(2*kt2+1)*16 + quad*4 + r];
        p0[r] = __expf(fminf(a0[r] + m0, 60.f));
        p1[r] = __expf(fminf(a1[r] + m1, 60.f));
      }
      uint2 u0, u1;
      u0.x = pk2(p0[0], p0[1]); u0.y = pk2(p0[2], p0[3]);
      u1.x = pk2(p1[0], p1[1]); u1.y = pk2(p1[2], p1[3]);
      *(uint2*)&Pl[w][l15][(2*kt2)*16   + quad*4] = u0;
      *(uint2*)&Pl[w][l15][(2*kt2+1)*16 + quad*4] = u1;
    }
    floatx4 o = {0.f,0.f,0.f,0.f};
    #pragma unroll
    for (int ks2=0; ks2<4; ks2++){
      short8 pa = *(const short8*)&Pl[w][l15][ks2*32 + quad*8];
      o = __builtin_amdgcn_mfma_f32_16x16x32_bf16(pa, vfrag[ks2], o, 0,0,0);
    }
    if (l15 < 8){
      #pragma unroll
      for (int r=0;r<4;r++){
        int q = q0 + quad*4 + r;
        pp[(size_t)ks*BSQ*64 + (size_t)(b*SEQ+q)*64 + h*8 + l15] = o[r];
      }
    } else if (l15 == 8){
      #pragma unroll
      for (int r=0;r<4;r++){
        int q = q0 + quad*4 + r;
        ps[(size_t)ks*BSQ*8 + (size_t)(b*SEQ+q)*8 + h] = o[r];
      }
    }
  }
}

// ---- attention combine: sum NSPLIT partials, normalize, emit bf16 ----------
__global__ __launch_bounds__(256) void t12_attn_comb(
    const float* __restrict__ pp, const float* __restrict__ ps,
    short* __restrict__ aout){
  int idx = blockIdx.x*256 + threadIdx.x;   // (bsq, h)
  if (idx >= BSQ*8) return;
  float s = 0.f;
  for (int k=0;k<NSPLIT;k++) s += ps[(size_t)k*BSQ*8 + idx];
  float inv = 1.f/s;
  int bsq = idx >> 3, h = idx & 7;
  size_t base = (size_t)bsq*64 + h*8;
  float o[8] = {};
  for (int k=0;k<NSPLIT;k++){
    const float4* p = (const float4*)(pp + (size_t)k*BSQ*64 + base);
    float4 a = p[0], bq = p[1];
    o[0]+=a.x; o[1]+=a.y; o[2]+=a.z; o[3]+=a.w;
    o[4]+=bq.x; o[5]+=bq.y; o[6]+=bq.z; o[7]+=bq.w;
  }
  short8 r;
  for (int d=0;d<8;d++) r[d] = f2b(o[d]*inv);
  *(short8*)(aout + base) = r;
}

// ---- add + LayerNorm (ddof=1), wave-per-row x4; xb/xc optional addends -----
__global__ __launch_bounds__(256) void t18_addnorm(
                 const float* __restrict__ xa, const float* __restrict__ xb,
                 const float* __restrict__ xc,
                 float* __restrict__ y, short* __restrict__ ybf,
                 float* __restrict__ accum, short* __restrict__ accbf,
                 const float* __restrict__ gamma, const float* __restrict__ beta,
                 int l){
  int w = threadIdx.x >> 6, lane = threadIdx.x & 63;
  int row = blockIdx.x*4 + w;
  size_t base  = (size_t)row*HIDD;
  size_t bbase = (size_t)row*320;
  float v[5];
  float s = 0.f, sq = 0.f;
  #pragma unroll
  for (int t=0;t<5;t++){
    int j = lane + t*64;
    float x = 0.f;
    if (j < HIDD){
      x = xa[base+j];
      if (xb) x += xb[base+j];
      if (xc) x += xc[base+j];
    }
    v[t] = x; s += x; sq += x*x;
  }
  #pragma unroll
  for (int off=32; off; off>>=1){ s += __shfl_down(s,off); sq += __shfl_down(sq,off); }
  s = __shfl(s, 0); sq = __shfl(sq, 0);
  float mu  = s * (1.0f/HIDD);
  float var = (sq - (float)HIDD*mu*mu) * (1.0f/(HIDD-1));
  float rstd = rsqrtf(var + 1e-8f);
  float g = gamma[l], be = beta[l];
  #pragma unroll
  for (int t=0;t<5;t++){
    int j = lane + t*64;
    if (j < HIDD){
      float o = g*(v[t]-mu)*rstd + be;
      if (y) y[base+j] = o;
      if (ybf) ybf[bbase+j] = f2b(o);
      if (accum){
        float a = accum[base+j] + o;
        accum[base+j] = a;
        if (accbf) accbf[bbase+j] = f2b(a);
      }
    } else if (j < 320){
      if (ybf) ybf[bbase+j] = 0;
      if (accbf) accbf[bbase+j] = 0;
    }
  }
}

// ---- colsum stage 1: block = (b, seq-chunk of 64); sum 64 rows ------------
__global__ __launch_bounds__(256) void t13_colsum_part(
    const float* __restrict__ outb, float* __restrict__ part){
  int blk = blockIdx.x;            // 256 blocks: b*8 + c
  int b = blk >> 3, c = blk & 7;
  int tid = threadIdx.x;
  size_t base = (size_t)b*SEQ*HIDD + (size_t)c*64*HIDD;
  int j1 = tid + 256;
  float s0 = 0.f, s1 = 0.f;
  for (int t = 0; t < 64; t++){
    const float* row = outb + base + (size_t)t*HIDD;
    s0 += row[tid];
    if (j1 < HIDD) s1 += row[j1];
  }
  float* dst = part + (size_t)(c*BATCH + b)*HIDD;
  dst[tid] = s0;
  if (j1 < HIDD) dst[j1] = s1;
}

// ---- colsum stage 2: fold 8 partials -> sums[32][300] ----------------------
__global__ void t13_colsum_comb(const float* __restrict__ part,
                                float* __restrict__ sums){
  int idx = blockIdx.x*256 + threadIdx.x;   // b*300 + j
  if (idx >= BATCH*HIDD) return;
  float s = 0.f;
  for (int c = 0; c < 8; c++) s += part[(size_t)c*BATCH*HIDD + idx];
  sums[idx] = s;
}

// ---- classifier GEMM, split-K=4 --------------------------------------------
__global__ __launch_bounds__(256) void t13_cls(
    const float* __restrict__ sums, const float* __restrict__ W,
    float* __restrict__ plog){
  int gid = blockIdx.x*256 + threadIdx.x;
  if (gid >= CLS_KS*BATCH*NCLS) return;
  int c = gid / (BATCH*NCLS);
  int rem = gid - c*(BATCH*NCLS);
  int m = rem / NCLS, n = rem - m*NCLS;
  const float* arow = sums + m*HIDD + c*CLS_KC;
  const float* wcol = W + (size_t)c*CLS_KC*NCLS + n;
  float acc = 0.f;
  #pragma unroll 5
  for (int k = 0; k < CLS_KC; k++)
    acc = fmaf(arow[k], wcol[(size_t)k*NCLS], acc);
  plog[gid] = acc;
}

// ---------------- classifier head: LayerNorm(ddof=1) + softmax -> fp32 -----
__device__ __forceinline__ float t10_bsum(float val, float* red){
  for (int off=32; off; off>>=1) val += __shfl_down(val, off);
  __syncthreads();
  if ((threadIdx.x & 63)==0) red[threadIdx.x>>6] = val;
  __syncthreads();
  return red[0]+red[1]+red[2]+red[3];
}
__device__ __forceinline__ float t10_bmax(float val, float* red){
  for (int off=32; off; off>>=1) val = fmaxf(val, __shfl_down(val, off));
  __syncthreads();
  if ((threadIdx.x & 63)==0) red[threadIdx.x>>6] = val;
  __syncthreads();
  return fmaxf(fmaxf(red[0],red[1]), fmaxf(red[2],red[3]));
}

__global__ __launch_bounds__(256) void t10_final(
                  const float* __restrict__ plog,
                  const float* __restrict__ gf, const float* __restrict__ bff,
                  float* __restrict__ outp){
  __shared__ float red[4];
  int b = blockIdx.x, tid = threadIdx.x;
  size_t base = (size_t)b*NCLS;
  float v[4];
  float s = 0.f, sq = 0.f;
  for (int t=0;t<4;t++){
    int j = tid + t*256;
    float x = 0.f;
    if (j < NCLS){
      for (int c=0;c<CLS_KS;c++) x += plog[(size_t)c*BATCH*NCLS + base + j];
    }
    v[t] = x; s += x; sq += x*x;
  }
  s  = t10_bsum(s, red);
  sq = t10_bsum(sq, red);
  float mu  = s * (1.0f/NCLS);
  float var = (sq - (float)NCLS*mu*mu) * (1.0f/(NCLS-1));
  float rstd = rsqrtf(var + 1e-8f);
  float g = gf[0], be = bff[0];
  float y[4]; float mx = -1e30f;
  for (int t=0;t<4;t++){
    int j = tid + t*256;
    y[t] = g*(v[t]-mu)*rstd + be;
    if (j < NCLS) mx = fmaxf(mx, y[t]);
  }
  mx = t10_bmax(mx, red);
  float p[4]; float es = 0.f;
  for (int t=0;t<4;t++){
    int j = tid + t*256;
    p[t] = (j < NCLS) ? __expf(y[t]-mx) : 0.f;
    es += p[t];
  }
  es = t10_bsum(es, red);
  float inv = 1.0f/es;
  for (int t=0;t<4;t++){
    int j = tid + t*256;
    if (j < NCLS) outp[base+j] = p[t]*inv;
  }
}

// ---------------------------------------------------------------------------
extern "C" void kernel_launch(void* const* d_in, const int* in_sizes, int n_in,
                              void* d_out, int out_size, void* d_ws, size_t ws_size,
                              hipStream_t stream){
  const int*   toks = (const int*)d_in[0];
  const float* emb  = (const float*)d_in[1];
  const float* WQ   = (const float*)d_in[2];
  const float* WK   = (const float*)d_in[3];
  const float* WV   = (const float*)d_in[4];
  const float* WO   = (const float*)d_in[5];
  const float* W1   = (const float*)d_in[6];
  const float* b1   = (const float*)d_in[7];
  const float* W2   = (const float*)d_in[8];
  const float* b2   = (const float*)d_in[9];
  const float* g1   = (const float*)d_in[10];
  const float* be1  = (const float*)d_in[11];
  const float* g2   = (const float*)d_in[12];
  const float* be2  = (const float*)d_in[13];
  const float* Vd   = (const float*)d_in[14];
  const float* gf   = (const float*)d_in[15];
  const float* bff  = (const float*)d_in[16];
  float* outp = (float*)d_out;

  // fp32 buffers
  float* acc    = (float*)d_ws;                         // [BSQ][300]
  float* xn     = acc    + (size_t)BSQ*HIDD;            // [BSQ][300]
  float* outb   = xn     + (size_t)BSQ*HIDD;            // [BSQ][300] (FF2 slice1 partial for all l; y at l==5)
  float* tmp    = outb   + (size_t)BSQ*HIDD;            // [BSQ][300]
  float* qkv    = tmp    + (size_t)BSQ*HIDD;            // slot: >= BSQ*QKVP bf16
  float* sums   = qkv    + (size_t)BSQ*192;             // [32][300]
  float* logits = sums   + BATCH*HIDD;                  // [32][1000] (pad)
  short* qkv_bf = (short*)qkv;                          // [BSQ][QKVP] bf16
  // attention partials alias tmp (dead during attention)
  float* pp     = tmp;
  float* ps     = tmp + (size_t)NSPLIT*BSQ*64;
  // bf16 buffers
  short* acc_bf = (short*)(logits + BATCH*NCLS);        // [BSQ][320]
  short* xn_bf  = acc_bf + (size_t)BSQ*320;             // [BSQ][320]
  short* aat_bf = xn_bf  + (size_t)BSQ*320;             // [BSQ][64]
  short* ff1_bf = aat_bf + (size_t)BSQ*64;              // [BSQ][1280]
  // bf16 weights (row counts padded to 128-tile multiples)
  short* wqkv = ff1_bf + (size_t)BSQ*1280;              // [6][256][320]
  short* wo   = wqkv + (size_t)6*256*320;               // [6][384][64]
  short* w1t  = wo   + (size_t)6*384*64;                // [6][1280][320]
  short* w2t  = w1t  + (size_t)6*1280*320;              // [6][384][1280]
  // classifier-tail fp32 buffers
  float* cspart = (float*)(w2t + (size_t)6*384*1280);   // [8][32][300]
  float* plog   = cspart + (size_t)8*BATCH*HIDD;        // [4][32][1000]

  {
    const float kscale = 0.057735026918962574f;         // 1/sqrt(300) into WK
    int tq = 6*64*320;
    prep_w<<<(tq+255)/256,256,0,stream>>>(WQ, wqkv, 300, 64, 320, 64, 0,   19200, 81920, tq, 1, 1.0f);
    prep_w<<<(tq+255)/256,256,0,stream>>>(WK, wqkv, 300, 64, 320, 64, 64,  19200, 81920, tq, 1, kscale);
    prep_w<<<(tq+255)/256,256,0,stream>>>(WV, wqkv, 300, 64, 320, 64, 128, 19200, 81920, tq, 1, 1.0f);
    prep_w<<<(tq+255)/256,256,0,stream>>>(WQ, wqkv, 300, 0,  320, 64, 192, 19200, 81920, tq, 0, 1.0f);
    int to = 6*384*64;
    prep_w<<<(to+255)/256,256,0,stream>>>(WO, wo, 64, 300, 64, 384, 0, 19200, 24576, to, 0, 1.0f);
    int t1 = 6*1280*320;
    prep_w<<<(t1+255)/256,256,0,stream>>>(W1, w1t, 300, 1200, 320, 1280, 0, 360000, 409600, t1, 0, 1.0f);
    int t2 = 6*384*1280;
    prep_w<<<(t2+255)/256,256,0,stream>>>(W2, w2t, 1200, 300, 1280, 384, 0, 360000, 491520, t2, 0, 1.0f);
  }

  t10_embed<<<(BSQ*320+255)/256, 256, 0, stream>>>(toks, emb, acc, acc_bf);

  for (int l = 0; l < NLAYERS; l++){
    // QKV: [BSQ][320]bf16 @ [256][320] -> qkv_bf [BSQ][256] bf16 (scale in WK)
    mm64<<<256*2,256,0,stream>>>(acc_bf, wqkv + (size_t)l*81920, nullptr, nullptr, qkv_bf,
                                 BSQ, 192, 320, QKVP, 2, 0);
    t18_attn<<<BATCH*NHEAD*NSPLIT, 256, 0, stream>>>(qkv_bf, toks, pp, ps);
    t12_attn_comb<<<(BSQ*8)/256, 256, 0, stream>>>(pp, ps, aat_bf);
    // WO: [BSQ][64]bf16 @ [384][64] -> tmp fp32 [BSQ][300]
    mm_a16<<<256*5,256,0,stream>>>(aat_bf, wo + (size_t)l*24576, nullptr, tmp, nullptr,
                                   BSQ, 300, 64, 0, 5, 0);
    t18_addnorm<<<BSQ/4,256,0,stream>>>(tmp, acc, nullptr, xn, xn_bf, nullptr, nullptr, g1, be1, l);
    // FF1: [BSQ][320]bf16 @ [1280][320] -> ff1 bf16 [BSQ][1280]
    mm128p<<<128*10,256,0,stream>>>(xn_bf, w1t + (size_t)l*409600, b1 + (size_t)l*FFD,
                                    nullptr, ff1_bf, BSQ, 1200, 320, 1280, 10, 1);
    // FF2 split-K=2: slice0 -> tmp (+b2), slice1 -> outb; grid 1536 (6/CU)
    mm64k<<<2*256*3,256,0,stream>>>(ff1_bf, w2t + (size_t)l*491520, b2 + (size_t)l*HIDD,
                                    tmp, outb, BSQ, 300, 1280, 640, 3);
    // an2 folds (tmp + outb) + xn; l<5: outb-y dead; l==5: acc accumulate dead
    t18_addnorm<<<BSQ/4,256,0,stream>>>(tmp, xn, outb, (l==NLAYERS-1)?outb:nullptr, nullptr,
                                        (l==NLAYERS-1)?nullptr:acc,
                                        (l==NLAYERS-1)?nullptr:acc_bf, g2, be2, l);
  }

  t13_colsum_part<<<BATCH*8, 256, 0, stream>>>(outb, cspart);
  t13_colsum_comb<<<(BATCH*HIDD+255)/256, 256, 0, stream>>>(cspart, sums);
  t13_cls<<<(CLS_KS*BATCH*NCLS)/256, 256, 0, stream>>>(sums, Vd, plog);
  t10_final<<<BATCH, 256, 0, stream>>>(plog, gf, bff, outp);

  hipStreamCaptureStatus cs = hipStreamCaptureStatusNone;
  hipStreamIsCapturing(stream, &cs);
  if (cs == hipStreamCaptureStatusNone){
    hipError_t e_sync = hipStreamSynchronize(stream);
    float ho[4] = {-1,-1,-1,-1};
    hipMemcpy(ho, d_out, 16, hipMemcpyDeviceToHost);
    fprintf(stderr, "[t20] sync=%s out[0..3]=%g,%g,%g,%g\n",
            hipGetErrorString(e_sync), ho[0], ho[1], ho[2], ho[3]);
    fflush(stderr);
  }
}

// Round 12
// 1082.177 us; speedup vs baseline: 1.0365x; 1.0225x over previous
//
#include <hip/hip_runtime.h>
#include <hip/hip_bf16.h>
#include <cstdio>
#include <cstdint>

#define BATCH 32
#define SEQ 512
#define BSQ (BATCH*SEQ)      // 16384
#define HIDD 300
#define HD 64
#define NHEAD 8
#define DHEAD 8
#define NLAYERS 6
#define FFD 1200
#define NCLS 1000
#define NSPLIT 4
#define KCH (SEQ/NSPLIT)     // 128 keys per block
#define QKVP 256             // bf16 qkv row stride (tile-rounded)
#define CLS_KS 4
#define CLS_KC (HIDD/CLS_KS) // 75

typedef short short8 __attribute__((ext_vector_type(8)));
typedef float floatx4 __attribute__((ext_vector_type(4)));

__device__ __forceinline__ short f2b(float v){
  __hip_bfloat16 h = __float2bfloat16(v);
  short s; __builtin_memcpy(&s, &h, 2); return s;
}
__device__ __forceinline__ unsigned pk2(float a, float b){
  return (unsigned)(unsigned short)f2b(a) | ((unsigned)(unsigned short)f2b(b) << 16);
}

// ------- embedding + positional encoding -> acc = 2*emb + pos (fp32 + bf16) -
__global__ void t10_embed(const int* __restrict__ toks,
                          const float* __restrict__ emb,
                          float* __restrict__ acc,
                          short* __restrict__ accbf){
  int idx = blockIdx.x*256 + threadIdx.x;
  if (idx >= BSQ*320) return;
  int row = idx / 320;
  int j   = idx - row*320;
  if (j >= HIDD){ accbf[(size_t)row*320 + j] = 0; return; }
  int t = toks[row];
  float e = emb[(size_t)t*HIDD + j];
  int s = row & (SEQ-1);
  float expo = (float)(j & ~1) * (1.0f/(float)HIDD);
  float ang  = (float)s * expf(-expo * 9.210340371976184f);
  float pe   = (j & 1) ? cosf(ang) : sinf(ang);
  float v = 2.0f*e + pe;
  acc[(size_t)row*HIDD + j] = v;
  accbf[(size_t)row*320 + j] = f2b(v);
}

// ------- weight prep: fp32 [K][N] -> bf16 transposed [Npad][Kpad] -----------
__global__ void prep_w(const float* __restrict__ src, short* __restrict__ dst,
                       int K, int N, int Kpad, int rows, int nbase,
                       int sls, int dls, int total, int perm, float smul){
  int idx = blockIdx.x*256 + threadIdx.x;
  if (idx >= total) return;
  int l   = idx / (rows*Kpad);
  int rem = idx - l*(rows*Kpad);
  int n = rem / Kpad;
  int k = rem - n*Kpad;
  int sc = perm ? ((n & 7)*8 + (n >> 3)) : n;
  float v = (n < N && k < K) ? src[(size_t)l*sls + (size_t)k*N + sc]*smul : 0.f;
  dst[(size_t)l*dls + (size_t)(nbase+n)*Kpad + k] = f2b(v);
}

// ---- bf16 MFMA GEMM, 64x64 tile (WO) ---------------------------------------
__global__ __launch_bounds__(256) void mm_a16(
    const short* __restrict__ A, const short* __restrict__ Wt,
    const float* __restrict__ bias, float* __restrict__ C,
    short* __restrict__ Cb,
    int M, int N, int Kpad, int Npad, int nnb, int relu){
  __shared__ short sA[64][40];
  __shared__ short sB[64][40];
  int wg = blockIdx.x;
  int cpx = gridDim.x >> 3;
  int swz = (wg & 7)*cpx + (wg >> 3);
  int mt = swz / nnb, nt = swz - mt*nnb;
  int m0 = mt*64, n0 = nt*64;
  int tid = threadIdx.x;
  int lane = tid & 63, wv = tid >> 6;
  int wm = (wv & 1)*32, wn = (wv >> 1)*32;
  int l15 = lane & 15, quad = lane >> 4;
  floatx4 acc[2][2] = {};
  int srow = tid >> 2, sko = (tid & 3)*8;
  const short* Arow = A  + (size_t)(m0 + srow)*Kpad + sko;
  const short* Brow = Wt + (size_t)(n0 + srow)*Kpad + sko;
  int nch = Kpad >> 5;
  for (int c = 0; c < nch; c++){
    int k0 = c*32;
    __syncthreads();
    *(short8*)&sA[srow][sko] = *(const short8*)(Arow + k0);
    *(short8*)&sB[srow][sko] = *(const short8*)(Brow + k0);
    __syncthreads();
    short8 af[2], bf[2];
    for (int i=0;i<2;i++)
      af[i] = *(const short8*)&sA[wm + i*16 + l15][quad*8];
    for (int j=0;j<2;j++)
      bf[j] = *(const short8*)&sB[wn + j*16 + l15][quad*8];
    for (int i=0;i<2;i++)
      for (int j=0;j<2;j++)
        acc[i][j] = __builtin_amdgcn_mfma_f32_16x16x32_bf16(af[i], bf[j], acc[i][j], 0,0,0);
  }
  if (Cb){
    for (int j=0;j<2;j++){
      int n = n0 + wn + j*16 + l15;
      float bv = (bias && n < N) ? bias[n] : 0.f;
      for (int i=0;i<2;i++){
        int mbase = m0 + wm + i*16 + quad*4;
        for (int r=0;r<4;r++){
          float cv = acc[i][j][r] + bv;
          if (relu) cv = fmaxf(cv, 0.f);
          Cb[(size_t)(mbase+r)*Npad + n] = (n < N) ? f2b(cv) : (short)0;
        }
      }
    }
  } else {
    for (int j=0;j<2;j++){
      int n = n0 + wn + j*16 + l15;
      if (n >= N) continue;
      float bv = bias ? bias[n] : 0.f;
      for (int i=0;i<2;i++){
        int mbase = m0 + wm + i*16 + quad*4;
        for (int r=0;r<4;r++){
          float cv = acc[i][j][r] + bv;
          if (relu) cv = fmaxf(cv, 0.f);
          C[(size_t)(mbase+r)*N + n] = cv;
        }
      }
    }
  }
}

// ---- bf16 MFMA GEMM, 64x128 tile, reg-staged, padded LDS (QKV / FF2) -------
__global__ __launch_bounds__(256) void mm64(
    const short* __restrict__ A, const short* __restrict__ Wt,
    const float* __restrict__ bias, float* __restrict__ C,
    short* __restrict__ Cb,
    int M, int N, int Kpad, int Npad, int nnb, int relu){
  __shared__ short sA[64][40];
  __shared__ short sB[128][40];
  int wg = blockIdx.x;
  int cpx = gridDim.x >> 3;
  int swz = (wg & 7)*cpx + (wg >> 3);
  int mt = swz / nnb, nt = swz - mt*nnb;
  int m0 = mt*64, n0 = nt*128;
  int tid = threadIdx.x;
  int lane = tid & 63, wv = tid >> 6;
  int l15 = lane & 15, quad = lane >> 4;
  int wn = wv*32;
  floatx4 acc[4][2] = {};
  int lr = tid >> 2, lc = (tid & 3)*8;
  const short* Arow  = A  + (size_t)(m0 + lr)*Kpad + lc;
  const short* Brow0 = Wt + (size_t)(n0 + lr)*Kpad + lc;
  const short* Brow1 = Wt + (size_t)(n0 + 64 + lr)*Kpad + lc;
  int nch = Kpad >> 5;
  for (int c = 0; c < nch; c++){
    int k0 = c*32;
    short8 va  = *(const short8*)(Arow  + k0);
    short8 vb0 = *(const short8*)(Brow0 + k0);
    short8 vb1 = *(const short8*)(Brow1 + k0);
    __syncthreads();
    *(short8*)&sA[lr][lc]      = va;
    *(short8*)&sB[lr][lc]      = vb0;
    *(short8*)&sB[64+lr][lc]   = vb1;
    __syncthreads();
    short8 af[4], bf[2];
    #pragma unroll
    for (int i=0;i<4;i++)
      af[i] = *(const short8*)&sA[i*16 + l15][quad*8];
    #pragma unroll
    for (int j=0;j<2;j++)
      bf[j] = *(const short8*)&sB[wn + j*16 + l15][quad*8];
    #pragma unroll
    for (int i=0;i<4;i++)
      #pragma unroll
      for (int j=0;j<2;j++)
        acc[i][j] = __builtin_amdgcn_mfma_f32_16x16x32_bf16(af[i], bf[j], acc[i][j], 0,0,0);
  }
  if (Cb){
    #pragma unroll
    for (int j=0;j<2;j++){
      int n = n0 + wn + j*16 + l15;
      float bv = (bias && n < N) ? bias[n] : 0.f;
      #pragma unroll
      for (int i=0;i<4;i++){
        int mbase = m0 + i*16 + quad*4;
        #pragma unroll
        for (int r=0;r<4;r++){
          float cv = acc[i][j][r] + bv;
          if (relu) cv = fmaxf(cv, 0.f);
          Cb[(size_t)(mbase+r)*Npad + n] = (n < N) ? f2b(cv) : (short)0;
        }
      }
    }
  } else {
    #pragma unroll
    for (int j=0;j<2;j++){
      int n = n0 + wn + j*16 + l15;
      if (n >= N) continue;
      float bv = bias ? bias[n] : 0.f;
      #pragma unroll
      for (int i=0;i<4;i++){
        int mbase = m0 + i*16 + quad*4;
        #pragma unroll
        for (int r=0;r<4;r++){
          float cv = acc[i][j][r] + bv;
          if (relu) cv = fmaxf(cv, 0.f);
          C[(size_t)(mbase+r)*N + n] = cv;
        }
      }
    }
  }
}

// ---- bf16 MFMA GEMM, 128x128 tile, reg-staged, padded LDS (FF1) ------------
__global__ __launch_bounds__(256) void mm128p(
    const short* __restrict__ A, const short* __restrict__ Wt,
    const float* __restrict__ bias, float* __restrict__ C,
    short* __restrict__ Cb,
    int M, int N, int Kpad, int Npad, int nnb, int relu){
  __shared__ short sA[128][40];
  __shared__ short sB[128][40];
  int wg = blockIdx.x;
  int cpx = gridDim.x >> 3;
  int swz = (wg & 7)*cpx + (wg >> 3);
  int mt = swz / nnb, nt = swz - mt*nnb;
  int m0 = mt*128, n0 = nt*128;
  int tid = threadIdx.x;
  int lane = tid & 63, wv = tid >> 6;
  int wm = (wv & 1)*64, wn = (wv >> 1)*64;
  int l15 = lane & 15, quad = lane >> 4;
  floatx4 acc[4][4] = {};
  int lr = tid >> 2, lc = (tid & 3)*8;
  const short* Arow0 = A  + (size_t)(m0 + lr)*Kpad + lc;
  const short* Arow1 = A  + (size_t)(m0 + 64 + lr)*Kpad + lc;
  const short* Brow0 = Wt + (size_t)(n0 + lr)*Kpad + lc;
  const short* Brow1 = Wt + (size_t)(n0 + 64 + lr)*Kpad + lc;
  int nch = Kpad >> 5;
  for (int c = 0; c < nch; c++){
    int k0 = c*32;
    short8 va0 = *(const short8*)(Arow0 + k0);
    short8 va1 = *(const short8*)(Arow1 + k0);
    short8 vb0 = *(const short8*)(Brow0 + k0);
    short8 vb1 = *(const short8*)(Brow1 + k0);
    __syncthreads();
    *(short8*)&sA[lr][lc]    = va0;
    *(short8*)&sA[64+lr][lc] = va1;
    *(short8*)&sB[lr][lc]    = vb0;
    *(short8*)&sB[64+lr][lc] = vb1;
    __syncthreads();
    short8 af[4], bf[4];
    #pragma unroll
    for (int i=0;i<4;i++)
      af[i] = *(const short8*)&sA[wm + i*16 + l15][quad*8];
    #pragma unroll
    for (int j=0;j<4;j++)
      bf[j] = *(const short8*)&sB[wn + j*16 + l15][quad*8];
    #pragma unroll
    for (int i=0;i<4;i++)
      #pragma unroll
      for (int j=0;j<4;j++)
        acc[i][j] = __builtin_amdgcn_mfma_f32_16x16x32_bf16(af[i], bf[j], acc[i][j], 0,0,0);
  }
  if (Cb){
    #pragma unroll
    for (int j=0;j<4;j++){
      int n = n0 + wn + j*16 + l15;
      float bv = (bias && n < N) ? bias[n] : 0.f;
      #pragma unroll
      for (int i=0;i<4;i++){
        int mbase = m0 + wm + i*16 + quad*4;
        #pragma unroll
        for (int r=0;r<4;r++){
          float cv = acc[i][j][r] + bv;
          if (relu) cv = fmaxf(cv, 0.f);
          Cb[(size_t)(mbase+r)*Npad + n] = (n < N) ? f2b(cv) : (short)0;
        }
      }
    }
  } else {
    #pragma unroll
    for (int j=0;j<4;j++){
      int n = n0 + wn + j*16 + l15;
      if (n >= N) continue;
      float bv = bias ? bias[n] : 0.f;
      #pragma unroll
      for (int i=0;i<4;i++){
        int mbase = m0 + wm + i*16 + quad*4;
        #pragma unroll
        for (int r=0;r<4;r++){
          float cv = acc[i][j][r] + bv;
          if (relu) cv = fmaxf(cv, 0.f);
          C[(size_t)(mbase+r)*N + n] = cv;
        }
      }
    }
  }
}

// ---- MFMA attention partial: qkv bf16 [BSQ][QKVP]; scale pre-folded --------
__global__ __launch_bounds__(256) void t18_attn(
    const short* __restrict__ qkvb, const int* __restrict__ toks,
    float* __restrict__ pp, float* __restrict__ ps){
  __shared__ short vb16[KCH][16];
  __shared__ float msk[KCH];
  __shared__ short Pl[4][16][136];
  int blk = blockIdx.x;
  int ks = blk & (NSPLIT-1);
  int bh = blk >> 2;
  int b = bh >> 3, h = bh & 7;
  int tid = threadIdx.x;
  int lane = tid & 63, w = tid >> 6;
  int quad = lane >> 4, l15 = lane & 15;
  int kbase = ks*KCH;
  if (tid < KCH){
    *(short8*)&vb16[tid][0] =
      *(const short8*)(qkvb + (size_t)(b*SEQ + kbase + tid)*QKVP + 128 + h*8);
  } else {
    int r = tid - KCH;
    msk[r] = (toks[b*SEQ + kbase + r]==0) ? -1e9f : 0.f;
  }
  __syncthreads();

  short8 kfrag[8];
  #pragma unroll
  for (int kt=0;kt<8;kt++){
    short8 f;
    #pragma unroll
    for (int j=0;j<8;j++) f[j] = 0;
    if (quad == 0)
      f = *(const short8*)(qkvb + (size_t)(b*SEQ + kbase + kt*16 + l15)*QKVP + 64 + h*8);
    kfrag[kt] = f;
  }
  short8 vfrag[4];
  #pragma unroll
  for (int ks2=0;ks2<4;ks2++){
    short8 f;
    #pragma unroll
    for (int j=0;j<8;j++) f[j] = 0;
    if (l15 < 8){
      #pragma unroll
      for (int j=0;j<8;j++) f[j] = vb16[ks2*32 + quad*8 + j][l15];
    } else if (l15 == 8){
      #pragma unroll
      for (int j=0;j<8;j++) f[j] = (short)0x3F80;
    }
    vfrag[ks2] = f;
  }

  for (int t = 0; t < 8; t++){
    int q0 = w*128 + t*16;
    short8 qf;
    #pragma unroll
    for (int j=0;j<8;j++) qf[j] = 0;
    if (quad == 0)
      qf = *(const short8*)(qkvb + (size_t)(b*SEQ + q0 + l15)*QKVP + h*8);
    #pragma unroll
    for (int kt2 = 0; kt2 < 4; kt2++){
      floatx4 z = {0.f,0.f,0.f,0.f};
      floatx4 a0 = __builtin_amdgcn_mfma_f32_16x16x32_bf16(kfrag[2*kt2],   qf, z, 0,0,0);
      floatx4 a1 = __builtin_amdgcn_mfma_f32_16x16x32_bf16(kfrag[2*kt2+1], qf, z, 0,0,0);
      float p0[4], p1[4];
      #pragma unroll
      for (int r=0;r<4;r++){
        float m0 = msk[(2*kt2)*16   + quad*4 + r];
        float m1 = msk[(2*kt2+1)*16 + quad*4 + r];
        p0[r] = __expf(fminf(a0[r] + m0, 60.f));
        p1[r] = __expf(fminf(a1[r] + m1, 60.f));
      }
      uint2 u0, u1;
      u0.x = pk2(p0[0], p0[1]); u0.y = pk2(p0[2], p0[3]);
      u1.x = pk2(p1[0], p1[1]); u1.y = pk2(p1[2], p1[3]);
      *(uint2*)&Pl[w][l15][(2*kt2)*16   + quad*4] = u0;
      *(uint2*)&Pl[w][l15][(2*kt2+1)*16 + quad*4] = u1;
    }
    floatx4 o = {0.f,0.f,0.f,0.f};
    #pragma unroll
    for (int ks2=0; ks2<4; ks2++){
      short8 pa = *(const short8*)&Pl[w][l15][ks2*32 + quad*8];
      o = __builtin_amdgcn_mfma_f32_16x16x32_bf16(pa, vfrag[ks2], o, 0,0,0);
    }
    if (l15 < 8){
      #pragma unroll
      for (int r=0;r<4;r++){
        int q = q0 + quad*4 + r;
        pp[(size_t)ks*BSQ*64 + (size_t)(b*SEQ+q)*64 + h*8 + l15] = o[r];
      }
    } else if (l15 == 8){
      #pragma unroll
      for (int r=0;r<4;r++){
        int q = q0 + quad*4 + r;
        ps[(size_t)ks*BSQ*8 + (size_t)(b*SEQ+q)*8 + h] = o[r];
      }
    }
  }
}

// ---- attention combine: sum NSPLIT partials, normalize, emit bf16 ----------
__global__ __launch_bounds__(256) void t12_attn_comb(
    const float* __restrict__ pp, const float* __restrict__ ps,
    short* __restrict__ aout){
  int idx = blockIdx.x*256 + threadIdx.x;   // (bsq, h)
  if (idx >= BSQ*8) return;
  float s = 0.f;
  for (int k=0;k<NSPLIT;k++) s += ps[(size_t)k*BSQ*8 + idx];
  float inv = 1.f/s;
  int bsq = idx >> 3, h = idx & 7;
  size_t base = (size_t)bsq*64 + h*8;
  float o[8] = {};
  for (int k=0;k<NSPLIT;k++){
    const float4* p = (const float4*)(pp + (size_t)k*BSQ*64 + base);
    float4 a = p[0], bq = p[1];
    o[0]+=a.x; o[1]+=a.y; o[2]+=a.z; o[3]+=a.w;
    o[4]+=bq.x; o[5]+=bq.y; o[6]+=bq.z; o[7]+=bq.w;
  }
  short8 r;
  for (int d=0;d<8;d++) r[d] = f2b(o[d]*inv);
  *(short8*)(aout + base) = r;
}

// ---- add + LayerNorm (ddof=1), wave-per-row x4; xb/xc optional addends -----
__global__ __launch_bounds__(256) void t18_addnorm(
                 const float* __restrict__ xa, const float* __restrict__ xb,
                 const float* __restrict__ xc,
                 float* __restrict__ y, short* __restrict__ ybf,
                 float* __restrict__ accum, short* __restrict__ accbf,
                 const float* __restrict__ gamma, const float* __restrict__ beta,
                 int l){
  int w = threadIdx.x >> 6, lane = threadIdx.x & 63;
  int row = blockIdx.x*4 + w;
  size_t base  = (size_t)row*HIDD;
  size_t bbase = (size_t)row*320;
  float v[5];
  float s = 0.f, sq = 0.f;
  #pragma unroll
  for (int t=0;t<5;t++){
    int j = lane + t*64;
    float x = 0.f;
    if (j < HIDD){
      x = xa[base+j];
      if (xb) x += xb[base+j];
      if (xc) x += xc[base+j];
    }
    v[t] = x; s += x; sq += x*x;
  }
  #pragma unroll
  for (int off=32; off; off>>=1){ s += __shfl_down(s,off); sq += __shfl_down(sq,off); }
  s = __shfl(s, 0); sq = __shfl(sq, 0);
  float mu  = s * (1.0f/HIDD);
  float var = (sq - (float)HIDD*mu*mu) * (1.0f/(HIDD-1));
  float rstd = rsqrtf(var + 1e-8f);
  float g = gamma[l], be = beta[l];
  #pragma unroll
  for (int t=0;t<5;t++){
    int j = lane + t*64;
    if (j < HIDD){
      float o = g*(v[t]-mu)*rstd + be;
      if (y) y[base+j] = o;
      if (ybf) ybf[bbase+j] = f2b(o);
      if (accum){
        float a = accum[base+j] + o;
        accum[base+j] = a;
        if (accbf) accbf[bbase+j] = f2b(a);
      }
    } else if (j < 320){
      if (ybf) ybf[bbase+j] = 0;
      if (accbf) accbf[bbase+j] = 0;
    }
  }
}

// ---- colsum stage 1: block = (b, seq-chunk of 64); sum 64 rows ------------
__global__ __launch_bounds__(256) void t13_colsum_part(
    const float* __restrict__ outb, float* __restrict__ part){
  int blk = blockIdx.x;            // 256 blocks: b*8 + c
  int b = blk >> 3, c = blk & 7;
  int tid = threadIdx.x;
  size_t base = (size_t)b*SEQ*HIDD + (size_t)c*64*HIDD;
  int j1 = tid + 256;
  float s0 = 0.f, s1 = 0.f;
  for (int t = 0; t < 64; t++){
    const float* row = outb + base + (size_t)t*HIDD;
    s0 += row[tid];
    if (j1 < HIDD) s1 += row[j1];
  }
  float* dst = part + (size_t)(c*BATCH + b)*HIDD;
  dst[tid] = s0;
  if (j1 < HIDD) dst[j1] = s1;
}

// ---- colsum stage 2: fold 8 partials -> sums[32][300] ----------------------
__global__ void t13_colsum_comb(const float* __restrict__ part,
                                float* __restrict__ sums){
  int idx = blockIdx.x*256 + threadIdx.x;   // b*300 + j
  if (idx >= BATCH*HIDD) return;
  float s = 0.f;
  for (int c = 0; c < 8; c++) s += part[(size_t)c*BATCH*HIDD + idx];
  sums[idx] = s;
}

// ---- classifier GEMM, split-K=4 --------------------------------------------
__global__ __launch_bounds__(256) void t13_cls(
    const float* __restrict__ sums, const float* __restrict__ W,
    float* __restrict__ plog){
  int gid = blockIdx.x*256 + threadIdx.x;
  if (gid >= CLS_KS*BATCH*NCLS) return;
  int c = gid / (BATCH*NCLS);
  int rem = gid - c*(BATCH*NCLS);
  int m = rem / NCLS, n = rem - m*NCLS;
  const float* arow = sums + m*HIDD + c*CLS_KC;
  const float* wcol = W + (size_t)c*CLS_KC*NCLS + n;
  float acc = 0.f;
  #pragma unroll 5
  for (int k = 0; k < CLS_KC; k++)
    acc = fmaf(arow[k], wcol[(size_t)k*NCLS], acc);
  plog[gid] = acc;
}

// ---------------- classifier head: LayerNorm(ddof=1) + softmax -> fp32 -----
__device__ __forceinline__ float t10_bsum(float val, float* red){
  for (int off=32; off; off>>=1) val += __shfl_down(val, off);
  __syncthreads();
  if ((threadIdx.x & 63)==0) red[threadIdx.x>>6] = val;
  __syncthreads();
  return red[0]+red[1]+red[2]+red[3];
}
__device__ __forceinline__ float t10_bmax(float val, float* red){
  for (int off=32; off; off>>=1) val = fmaxf(val, __shfl_down(val, off));
  __syncthreads();
  if ((threadIdx.x & 63)==0) red[threadIdx.x>>6] = val;
  __syncthreads();
  return fmaxf(fmaxf(red[0],red[1]), fmaxf(red[2],red[3]));
}

__global__ __launch_bounds__(256) void t10_final(
                  const float* __restrict__ plog,
                  const float* __restrict__ gf, const float* __restrict__ bff,
                  float* __restrict__ outp){
  __shared__ float red[4];
  int b = blockIdx.x, tid = threadIdx.x;
  size_t base = (size_t)b*NCLS;
  float v[4];
  float s = 0.f, sq = 0.f;
  for (int t=0;t<4;t++){
    int j = tid + t*256;
    float x = 0.f;
    if (j < NCLS){
      for (int c=0;c<CLS_KS;c++) x += plog[(size_t)c*BATCH*NCLS + base + j];
    }
    v[t] = x; s += x; sq += x*x;
  }
  s  = t10_bsum(s, red);
  sq = t10_bsum(sq, red);
  float mu  = s * (1.0f/NCLS);
  float var = (sq - (float)NCLS*mu*mu) * (1.0f/(NCLS-1));
  float rstd = rsqrtf(var + 1e-8f);
  float g = gf[0], be = bff[0];
  float y[4]; float mx = -1e30f;
  for (int t=0;t<4;t++){
    int j = tid + t*256;
    y[t] = g*(v[t]-mu)*rstd + be;
    if (j < NCLS) mx = fmaxf(mx, y[t]);
  }
  mx = t10_bmax(mx, red);
  float p[4]; float es = 0.f;
  for (int t=0;t<4;t++){
    int j = tid + t*256;
    p[t] = (j < NCLS) ? __expf(y[t]-mx) : 0.f;
    es += p[t];
  }
  es = t10_bsum(es, red);
  float inv = 1.0f/es;
  for (int t=0;t<4;t++){
    int j = tid + t*256;
    if (j < NCLS) outp[base+j] = p[t]*inv;
  }
}

// ---------------------------------------------------------------------------
extern "C" void kernel_launch(void* const* d_in, const int* in_sizes, int n_in,
                              void* d_out, int out_size, void* d_ws, size_t ws_size,
                              hipStream_t stream){
  const int*   toks = (const int*)d_in[0];
  const float* emb  = (const float*)d_in[1];
  const float* WQ   = (const float*)d_in[2];
  const float* WK   = (const float*)d_in[3];
  const float* WV   = (const float*)d_in[4];
  const float* WO   = (const float*)d_in[5];
  const float* W1   = (const float*)d_in[6];
  const float* b1   = (const float*)d_in[7];
  const float* W2   = (const float*)d_in[8];
  const float* b2   = (const float*)d_in[9];
  const float* g1   = (const float*)d_in[10];
  const float* be1  = (const float*)d_in[11];
  const float* g2   = (const float*)d_in[12];
  const float* be2  = (const float*)d_in[13];
  const float* Vd   = (const float*)d_in[14];
  const float* gf   = (const float*)d_in[15];
  const float* bff  = (const float*)d_in[16];
  float* outp = (float*)d_out;

  // fp32 buffers
  float* acc    = (float*)d_ws;                         // [BSQ][300]
  float* xn     = acc    + (size_t)BSQ*HIDD;            // [BSQ][300]
  float* outb   = xn     + (size_t)BSQ*HIDD;            // [BSQ][300]
  float* tmp    = outb   + (size_t)BSQ*HIDD;            // [BSQ][300]
  float* qkv    = tmp    + (size_t)BSQ*HIDD;            // slot: >= BSQ*QKVP bf16
  float* sums   = qkv    + (size_t)BSQ*192;             // [32][300]
  float* logits = sums   + BATCH*HIDD;                  // [32][1000] (pad)
  short* qkv_bf = (short*)qkv;                          // [BSQ][QKVP] bf16
  // attention partials alias tmp (dead during attention)
  float* pp     = tmp;
  float* ps     = tmp + (size_t)NSPLIT*BSQ*64;
  // bf16 buffers
  short* acc_bf = (short*)(logits + BATCH*NCLS);        // [BSQ][320]
  short* xn_bf  = acc_bf + (size_t)BSQ*320;             // [BSQ][320]
  short* aat_bf = xn_bf  + (size_t)BSQ*320;             // [BSQ][64]
  short* ff1_bf = aat_bf + (size_t)BSQ*64;              // [BSQ][1280]
  // bf16 weights (row counts padded to 128-tile multiples)
  short* wqkv = ff1_bf + (size_t)BSQ*1280;              // [6][256][320]
  short* wo   = wqkv + (size_t)6*256*320;               // [6][384][64]
  short* w1t  = wo   + (size_t)6*384*64;                // [6][1280][320]
  short* w2t  = w1t  + (size_t)6*1280*320;              // [6][384][1280]
  // classifier-tail fp32 buffers
  float* cspart = (float*)(w2t + (size_t)6*384*1280);   // [8][32][300]
  float* plog   = cspart + (size_t)8*BATCH*HIDD;        // [4][32][1000]

  {
    const float kscale = 0.057735026918962574f;         // 1/sqrt(300) into WK
    int tq = 6*64*320;
    prep_w<<<(tq+255)/256,256,0,stream>>>(WQ, wqkv, 300, 64, 320, 64, 0,   19200, 81920, tq, 1, 1.0f);
    prep_w<<<(tq+255)/256,256,0,stream>>>(WK, wqkv, 300, 64, 320, 64, 64,  19200, 81920, tq, 1, kscale);
    prep_w<<<(tq+255)/256,256,0,stream>>>(WV, wqkv, 300, 64, 320, 64, 128, 19200, 81920, tq, 1, 1.0f);
    prep_w<<<(tq+255)/256,256,0,stream>>>(WQ, wqkv, 300, 0,  320, 64, 192, 19200, 81920, tq, 0, 1.0f);
    int to = 6*384*64;
    prep_w<<<(to+255)/256,256,0,stream>>>(WO, wo, 64, 300, 64, 384, 0, 19200, 24576, to, 0, 1.0f);
    int t1 = 6*1280*320;
    prep_w<<<(t1+255)/256,256,0,stream>>>(W1, w1t, 300, 1200, 320, 1280, 0, 360000, 409600, t1, 0, 1.0f);
    int t2 = 6*384*1280;
    prep_w<<<(t2+255)/256,256,0,stream>>>(W2, w2t, 1200, 300, 1280, 384, 0, 360000, 491520, t2, 0, 1.0f);
  }

  t10_embed<<<(BSQ*320+255)/256, 256, 0, stream>>>(toks, emb, acc, acc_bf);

  for (int l = 0; l < NLAYERS; l++){
    // QKV: [BSQ][320]bf16 @ [256][320] -> qkv_bf [BSQ][256] bf16 (scale in WK)
    mm64<<<256*2,256,0,stream>>>(acc_bf, wqkv + (size_t)l*81920, nullptr, nullptr, qkv_bf,
                                 BSQ, 192, 320, QKVP, 2, 0);
    t18_attn<<<BATCH*NHEAD*NSPLIT, 256, 0, stream>>>(qkv_bf, toks, pp, ps);
    t12_attn_comb<<<(BSQ*8)/256, 256, 0, stream>>>(pp, ps, aat_bf);
    // WO: [BSQ][64]bf16 @ [384][64] -> tmp fp32 [BSQ][300]
    mm_a16<<<256*5,256,0,stream>>>(aat_bf, wo + (size_t)l*24576, nullptr, tmp, nullptr,
                                   BSQ, 300, 64, 0, 5, 0);
    t18_addnorm<<<BSQ/4,256,0,stream>>>(tmp, acc, nullptr, xn, xn_bf, nullptr, nullptr, g1, be1, l);
    // FF1: [BSQ][320]bf16 @ [1280][320] -> ff1 bf16 [BSQ][1280]
    mm128p<<<128*10,256,0,stream>>>(xn_bf, w1t + (size_t)l*409600, b1 + (size_t)l*FFD,
                                    nullptr, ff1_bf, BSQ, 1200, 320, 1280, 10, 1);
    // FF2: [BSQ][1280]bf16 @ [384][1280] -> tmp fp32 [BSQ][300] (round-9 config)
    mm64<<<256*3,256,0,stream>>>(ff1_bf, w2t + (size_t)l*491520, b2 + (size_t)l*HIDD,
                                 tmp, nullptr, BSQ, 300, 1280, 0, 3, 0);
    // l<5: outb write dead; l==5: acc accumulate dead
    t18_addnorm<<<BSQ/4,256,0,stream>>>(tmp, xn, nullptr, (l==NLAYERS-1)?outb:nullptr, nullptr,
                                        (l==NLAYERS-1)?nullptr:acc,
                                        (l==NLAYERS-1)?nullptr:acc_bf, g2, be2, l);
  }

  t13_colsum_part<<<BATCH*8, 256, 0, stream>>>(outb, cspart);
  t13_colsum_comb<<<(BATCH*HIDD+255)/256, 256, 0, stream>>>(cspart, sums);
  t13_cls<<<(CLS_KS*BATCH*NCLS)/256, 256, 0, stream>>>(sums, Vd, plog);
  t10_final<<<BATCH, 256, 0, stream>>>(plog, gf, bff, outp);

  hipStreamCaptureStatus cs = hipStreamCaptureStatusNone;
  hipStreamIsCapturing(stream, &cs);
  if (cs == hipStreamCaptureStatusNone){
    hipError_t e_sync = hipStreamSynchronize(stream);
    float ho[4] = {-1,-1,-1,-1};
    hipMemcpy(ho, d_out, 16, hipMemcpyDeviceToHost);
    fprintf(stderr, "[t21] sync=%s out[0..3]=%g,%g,%g,%g\n",
            hipGetErrorString(e_sync), ho[0], ho[1], ho[2], ho[3]);
    fflush(stderr);
  }
}

// Round 13
// 1046.259 us; speedup vs baseline: 1.0720x; 1.0343x over previous
//
#include <hip/hip_runtime.h>
#include <hip/hip_bf16.h>
#include <cstdio>
#include <cstdint>

#define BATCH 32
#define SEQ 512
#define BSQ (BATCH*SEQ)      // 16384
#define HIDD 300
#define HD 64
#define NHEAD 8
#define DHEAD 8
#define NLAYERS 6
#define FFD 1200
#define NCLS 1000
#define NSPLIT 4
#define KCH (SEQ/NSPLIT)     // 128 keys per block
#define QKVP 256             // bf16 qkv row stride (tile-rounded)
#define CLS_KS 4
#define CLS_KC (HIDD/CLS_KS) // 75

typedef short short8 __attribute__((ext_vector_type(8)));
typedef float floatx4 __attribute__((ext_vector_type(4)));

__device__ __forceinline__ short f2b(float v){
  __hip_bfloat16 h = __float2bfloat16(v);
  short s; __builtin_memcpy(&s, &h, 2); return s;
}
__device__ __forceinline__ unsigned pk2(float a, float b){
  return (unsigned)(unsigned short)f2b(a) | ((unsigned)(unsigned short)f2b(b) << 16);
}

// ------- embedding + positional encoding -> acc = 2*emb + pos (fp32 + bf16) -
__global__ void t10_embed(const int* __restrict__ toks,
                          const float* __restrict__ emb,
                          float* __restrict__ acc,
                          short* __restrict__ accbf){
  int idx = blockIdx.x*256 + threadIdx.x;
  if (idx >= BSQ*320) return;
  int row = idx / 320;
  int j   = idx - row*320;
  if (j >= HIDD){ accbf[(size_t)row*320 + j] = 0; return; }
  int t = toks[row];
  float e = emb[(size_t)t*HIDD + j];
  int s = row & (SEQ-1);
  float expo = (float)(j & ~1) * (1.0f/(float)HIDD);
  float ang  = (float)s * expf(-expo * 9.210340371976184f);
  float pe   = (j & 1) ? cosf(ang) : sinf(ang);
  float v = 2.0f*e + pe;
  acc[(size_t)row*HIDD + j] = v;
  accbf[(size_t)row*320 + j] = f2b(v);
}

// ------- weight prep: fp32 [K][N] -> bf16 transposed [Npad][Kpad] -----------
__global__ void prep_w(const float* __restrict__ src, short* __restrict__ dst,
                       int K, int N, int Kpad, int rows, int nbase,
                       int sls, int dls, int total, int perm, float smul){
  int idx = blockIdx.x*256 + threadIdx.x;
  if (idx >= total) return;
  int l   = idx / (rows*Kpad);
  int rem = idx - l*(rows*Kpad);
  int n = rem / Kpad;
  int k = rem - n*Kpad;
  int sc = perm ? ((n & 7)*8 + (n >> 3)) : n;
  float v = (n < N && k < K) ? src[(size_t)l*sls + (size_t)k*N + sc]*smul : 0.f;
  dst[(size_t)l*dls + (size_t)(nbase+n)*Kpad + k] = f2b(v);
}

// ---- bf16 MFMA GEMM, 64x64 tile (WO) ---------------------------------------
__global__ __launch_bounds__(256) void mm_a16(
    const short* __restrict__ A, const short* __restrict__ Wt,
    const float* __restrict__ bias, float* __restrict__ C,
    short* __restrict__ Cb,
    int M, int N, int Kpad, int Npad, int nnb, int relu){
  __shared__ short sA[64][40];
  __shared__ short sB[64][40];
  int wg = blockIdx.x;
  int cpx = gridDim.x >> 3;
  int swz = (wg & 7)*cpx + (wg >> 3);
  int mt = swz / nnb, nt = swz - mt*nnb;
  int m0 = mt*64, n0 = nt*64;
  int tid = threadIdx.x;
  int lane = tid & 63, wv = tid >> 6;
  int wm = (wv & 1)*32, wn = (wv >> 1)*32;
  int l15 = lane & 15, quad = lane >> 4;
  floatx4 acc[2][2] = {};
  int srow = tid >> 2, sko = (tid & 3)*8;
  const short* Arow = A  + (size_t)(m0 + srow)*Kpad + sko;
  const short* Brow = Wt + (size_t)(n0 + srow)*Kpad + sko;
  int nch = Kpad >> 5;
  for (int c = 0; c < nch; c++){
    int k0 = c*32;
    __syncthreads();
    *(short8*)&sA[srow][sko] = *(const short8*)(Arow + k0);
    *(short8*)&sB[srow][sko] = *(const short8*)(Brow + k0);
    __syncthreads();
    short8 af[2], bf[2];
    for (int i=0;i<2;i++)
      af[i] = *(const short8*)&sA[wm + i*16 + l15][quad*8];
    for (int j=0;j<2;j++)
      bf[j] = *(const short8*)&sB[wn + j*16 + l15][quad*8];
    for (int i=0;i<2;i++)
      for (int j=0;j<2;j++)
        acc[i][j] = __builtin_amdgcn_mfma_f32_16x16x32_bf16(af[i], bf[j], acc[i][j], 0,0,0);
  }
  if (Cb){
    for (int j=0;j<2;j++){
      int n = n0 + wn + j*16 + l15;
      float bv = (bias && n < N) ? bias[n] : 0.f;
      for (int i=0;i<2;i++){
        int mbase = m0 + wm + i*16 + quad*4;
        for (int r=0;r<4;r++){
          float cv = acc[i][j][r] + bv;
          if (relu) cv = fmaxf(cv, 0.f);
          Cb[(size_t)(mbase+r)*Npad + n] = (n < N) ? f2b(cv) : (short)0;
        }
      }
    }
  } else {
    for (int j=0;j<2;j++){
      int n = n0 + wn + j*16 + l15;
      if (n >= N) continue;
      float bv = bias ? bias[n] : 0.f;
      for (int i=0;i<2;i++){
        int mbase = m0 + wm + i*16 + quad*4;
        for (int r=0;r<4;r++){
          float cv = acc[i][j][r] + bv;
          if (relu) cv = fmaxf(cv, 0.f);
          C[(size_t)(mbase+r)*N + n] = cv;
        }
      }
    }
  }
}

// ---- bf16 MFMA GEMM, 64x128 tile, reg-staged, padded LDS (QKV) -------------
__global__ __launch_bounds__(256) void mm64(
    const short* __restrict__ A, const short* __restrict__ Wt,
    const float* __restrict__ bias, float* __restrict__ C,
    short* __restrict__ Cb,
    int M, int N, int Kpad, int Npad, int nnb, int relu){
  __shared__ short sA[64][40];
  __shared__ short sB[128][40];
  int wg = blockIdx.x;
  int cpx = gridDim.x >> 3;
  int swz = (wg & 7)*cpx + (wg >> 3);
  int mt = swz / nnb, nt = swz - mt*nnb;
  int m0 = mt*64, n0 = nt*128;
  int tid = threadIdx.x;
  int lane = tid & 63, wv = tid >> 6;
  int l15 = lane & 15, quad = lane >> 4;
  int wn = wv*32;
  floatx4 acc[4][2] = {};
  int lr = tid >> 2, lc = (tid & 3)*8;
  const short* Arow  = A  + (size_t)(m0 + lr)*Kpad + lc;
  const short* Brow0 = Wt + (size_t)(n0 + lr)*Kpad + lc;
  const short* Brow1 = Wt + (size_t)(n0 + 64 + lr)*Kpad + lc;
  int nch = Kpad >> 5;
  for (int c = 0; c < nch; c++){
    int k0 = c*32;
    short8 va  = *(const short8*)(Arow  + k0);
    short8 vb0 = *(const short8*)(Brow0 + k0);
    short8 vb1 = *(const short8*)(Brow1 + k0);
    __syncthreads();
    *(short8*)&sA[lr][lc]      = va;
    *(short8*)&sB[lr][lc]      = vb0;
    *(short8*)&sB[64+lr][lc]   = vb1;
    __syncthreads();
    short8 af[4], bf[2];
    #pragma unroll
    for (int i=0;i<4;i++)
      af[i] = *(const short8*)&sA[i*16 + l15][quad*8];
    #pragma unroll
    for (int j=0;j<2;j++)
      bf[j] = *(const short8*)&sB[wn + j*16 + l15][quad*8];
    #pragma unroll
    for (int i=0;i<4;i++)
      #pragma unroll
      for (int j=0;j<2;j++)
        acc[i][j] = __builtin_amdgcn_mfma_f32_16x16x32_bf16(af[i], bf[j], acc[i][j], 0,0,0);
  }
  if (Cb){
    #pragma unroll
    for (int j=0;j<2;j++){
      int n = n0 + wn + j*16 + l15;
      float bv = (bias && n < N) ? bias[n] : 0.f;
      #pragma unroll
      for (int i=0;i<4;i++){
        int mbase = m0 + i*16 + quad*4;
        #pragma unroll
        for (int r=0;r<4;r++){
          float cv = acc[i][j][r] + bv;
          if (relu) cv = fmaxf(cv, 0.f);
          Cb[(size_t)(mbase+r)*Npad + n] = (n < N) ? f2b(cv) : (short)0;
        }
      }
    }
  } else {
    #pragma unroll
    for (int j=0;j<2;j++){
      int n = n0 + wn + j*16 + l15;
      if (n >= N) continue;
      float bv = bias ? bias[n] : 0.f;
      #pragma unroll
      for (int i=0;i<4;i++){
        int mbase = m0 + i*16 + quad*4;
        #pragma unroll
        for (int r=0;r<4;r++){
          float cv = acc[i][j][r] + bv;
          if (relu) cv = fmaxf(cv, 0.f);
          C[(size_t)(mbase+r)*N + n] = cv;
        }
      }
    }
  }
}

// ---- bf16 MFMA GEMM, 64x128 tile, BK=64 (FF2): half the barrier events -----
// 20 chunks of K=64 instead of 40 of K=32: 16 MFMAs per barrier pair/wave.
// LDS 27.6 KB (still >=3 blocks/CU).  [*][72] rows: frag-read bank =
// (36r + c/2)%32 -> 2 lanes/bank = conflict-free.  MFMA K-order identical
// to BK=32 (ascending 32-chunks) -> bit-identical output.
__global__ __launch_bounds__(256) void mm64b(
    const short* __restrict__ A, const short* __restrict__ Wt,
    const float* __restrict__ bias, float* __restrict__ C,
    int M, int N, int Kpad, int nnb){
  __shared__ short sA[64][72];
  __shared__ short sB[128][72];
  int wg = blockIdx.x;
  int cpx = gridDim.x >> 3;
  int swz = (wg & 7)*cpx + (wg >> 3);
  int mt = swz / nnb, nt = swz - mt*nnb;
  int m0 = mt*64, n0 = nt*128;
  int tid = threadIdx.x;
  int lane = tid & 63, wv = tid >> 6;
  int l15 = lane & 15, quad = lane >> 4;
  int wn = wv*32;
  floatx4 acc[4][2] = {};
  int lr = tid >> 2, lc = (tid & 3)*16;      // 4 threads x 16 cols cover K=64
  const short* Arow  = A  + (size_t)(m0 + lr)*Kpad + lc;
  const short* Brow0 = Wt + (size_t)(n0 + lr)*Kpad + lc;
  const short* Brow1 = Wt + (size_t)(n0 + 64 + lr)*Kpad + lc;
  int nch = Kpad >> 6;
  for (int c = 0; c < nch; c++){
    int k0 = c*64;
    short8 va0 = *(const short8*)(Arow  + k0);
    short8 va1 = *(const short8*)(Arow  + k0 + 8);
    short8 vb0 = *(const short8*)(Brow0 + k0);
    short8 vb1 = *(const short8*)(Brow0 + k0 + 8);
    short8 vc0 = *(const short8*)(Brow1 + k0);
    short8 vc1 = *(const short8*)(Brow1 + k0 + 8);
    __syncthreads();
    *(short8*)&sA[lr][lc]       = va0;
    *(short8*)&sA[lr][lc+8]     = va1;
    *(short8*)&sB[lr][lc]       = vb0;
    *(short8*)&sB[lr][lc+8]     = vb1;
    *(short8*)&sB[64+lr][lc]    = vc0;
    *(short8*)&sB[64+lr][lc+8]  = vc1;
    __syncthreads();
    #pragma unroll
    for (int h = 0; h < 2; h++){
      int ko = h*32 + quad*8;
      short8 af[4], bf[2];
      #pragma unroll
      for (int i=0;i<4;i++)
        af[i] = *(const short8*)&sA[i*16 + l15][ko];
      #pragma unroll
      for (int j=0;j<2;j++)
        bf[j] = *(const short8*)&sB[wn + j*16 + l15][ko];
      #pragma unroll
      for (int i=0;i<4;i++)
        #pragma unroll
        for (int j=0;j<2;j++)
          acc[i][j] = __builtin_amdgcn_mfma_f32_16x16x32_bf16(af[i], bf[j], acc[i][j], 0,0,0);
    }
  }
  #pragma unroll
  for (int j=0;j<2;j++){
    int n = n0 + wn + j*16 + l15;
    if (n >= N) continue;
    float bv = bias ? bias[n] : 0.f;
    #pragma unroll
    for (int i=0;i<4;i++){
      int mbase = m0 + i*16 + quad*4;
      #pragma unroll
      for (int r=0;r<4;r++)
        C[(size_t)(mbase+r)*N + n] = acc[i][j][r] + bv;
    }
  }
}

// ---- bf16 MFMA GEMM, 128x128 tile, reg-staged, padded LDS (FF1) ------------
__global__ __launch_bounds__(256) void mm128p(
    const short* __restrict__ A, const short* __restrict__ Wt,
    const float* __restrict__ bias, float* __restrict__ C,
    short* __restrict__ Cb,
    int M, int N, int Kpad, int Npad, int nnb, int relu){
  __shared__ short sA[128][40];
  __shared__ short sB[128][40];
  int wg = blockIdx.x;
  int cpx = gridDim.x >> 3;
  int swz = (wg & 7)*cpx + (wg >> 3);
  int mt = swz / nnb, nt = swz - mt*nnb;
  int m0 = mt*128, n0 = nt*128;
  int tid = threadIdx.x;
  int lane = tid & 63, wv = tid >> 6;
  int wm = (wv & 1)*64, wn = (wv >> 1)*64;
  int l15 = lane & 15, quad = lane >> 4;
  floatx4 acc[4][4] = {};
  int lr = tid >> 2, lc = (tid & 3)*8;
  const short* Arow0 = A  + (size_t)(m0 + lr)*Kpad + lc;
  const short* Arow1 = A  + (size_t)(m0 + 64 + lr)*Kpad + lc;
  const short* Brow0 = Wt + (size_t)(n0 + lr)*Kpad + lc;
  const short* Brow1 = Wt + (size_t)(n0 + 64 + lr)*Kpad + lc;
  int nch = Kpad >> 5;
  for (int c = 0; c < nch; c++){
    int k0 = c*32;
    short8 va0 = *(const short8*)(Arow0 + k0);
    short8 va1 = *(const short8*)(Arow1 + k0);
    short8 vb0 = *(const short8*)(Brow0 + k0);
    short8 vb1 = *(const short8*)(Brow1 + k0);
    __syncthreads();
    *(short8*)&sA[lr][lc]    = va0;
    *(short8*)&sA[64+lr][lc] = va1;
    *(short8*)&sB[lr][lc]    = vb0;
    *(short8*)&sB[64+lr][lc] = vb1;
    __syncthreads();
    short8 af[4], bf[4];
    #pragma unroll
    for (int i=0;i<4;i++)
      af[i] = *(const short8*)&sA[wm + i*16 + l15][quad*8];
    #pragma unroll
    for (int j=0;j<4;j++)
      bf[j] = *(const short8*)&sB[wn + j*16 + l15][quad*8];
    #pragma unroll
    for (int i=0;i<4;i++)
      #pragma unroll
      for (int j=0;j<4;j++)
        acc[i][j] = __builtin_amdgcn_mfma_f32_16x16x32_bf16(af[i], bf[j], acc[i][j], 0,0,0);
  }
  if (Cb){
    #pragma unroll
    for (int j=0;j<4;j++){
      int n = n0 + wn + j*16 + l15;
      float bv = (bias && n < N) ? bias[n] : 0.f;
      #pragma unroll
      for (int i=0;i<4;i++){
        int mbase = m0 + wm + i*16 + quad*4;
        #pragma unroll
        for (int r=0;r<4;r++){
          float cv = acc[i][j][r] + bv;
          if (relu) cv = fmaxf(cv, 0.f);
          Cb[(size_t)(mbase+r)*Npad + n] = (n < N) ? f2b(cv) : (short)0;
        }
      }
    }
  } else {
    #pragma unroll
    for (int j=0;j<4;j++){
      int n = n0 + wn + j*16 + l15;
      if (n >= N) continue;
      float bv = bias ? bias[n] : 0.f;
      #pragma unroll
      for (int i=0;i<4;i++){
        int mbase = m0 + wm + i*16 + quad*4;
        #pragma unroll
        for (int r=0;r<4;r++){
          float cv = acc[i][j][r] + bv;
          if (relu) cv = fmaxf(cv, 0.f);
          C[(size_t)(mbase+r)*N + n] = cv;
        }
      }
    }
  }
}

// ---- MFMA attention partial: qkv bf16 [BSQ][QKVP]; scale pre-folded --------
__global__ __launch_bounds__(256) void t18_attn(
    const short* __restrict__ qkvb, const int* __restrict__ toks,
    float* __restrict__ pp, float* __restrict__ ps){
  __shared__ short vb16[KCH][16];
  __shared__ float msk[KCH];
  __shared__ short Pl[4][16][136];
  int blk = blockIdx.x;
  int ks = blk & (NSPLIT-1);
  int bh = blk >> 2;
  int b = bh >> 3, h = bh & 7;
  int tid = threadIdx.x;
  int lane = tid & 63, w = tid >> 6;
  int quad = lane >> 4, l15 = lane & 15;
  int kbase = ks*KCH;
  if (tid < KCH){
    *(short8*)&vb16[tid][0] =
      *(const short8*)(qkvb + (size_t)(b*SEQ + kbase + tid)*QKVP + 128 + h*8);
  } else {
    int r = tid - KCH;
    msk[r] = (toks[b*SEQ + kbase + r]==0) ? -1e9f : 0.f;
  }
  __syncthreads();

  short8 kfrag[8];
  #pragma unroll
  for (int kt=0;kt<8;kt++){
    short8 f;
    #pragma unroll
    for (int j=0;j<8;j++) f[j] = 0;
    if (quad == 0)
      f = *(const short8*)(qkvb + (size_t)(b*SEQ + kbase + kt*16 + l15)*QKVP + 64 + h*8);
    kfrag[kt] = f;
  }
  short8 vfrag[4];
  #pragma unroll
  for (int ks2=0;ks2<4;ks2++){
    short8 f;
    #pragma unroll
    for (int j=0;j<8;j++) f[j] = 0;
    if (l15 < 8){
      #pragma unroll
      for (int j=0;j<8;j++) f[j] = vb16[ks2*32 + quad*8 + j][l15];
    } else if (l15 == 8){
      #pragma unroll
      for (int j=0;j<8;j++) f[j] = (short)0x3F80;
    }
    vfrag[ks2] = f;
  }

  for (int t = 0; t < 8; t++){
    int q0 = w*128 + t*16;
    short8 qf;
    #pragma unroll
    for (int j=0;j<8;j++) qf[j] = 0;
    if (quad == 0)
      qf = *(const short8*)(qkvb + (size_t)(b*SEQ + q0 + l15)*QKVP + h*8);
    #pragma unroll
    for (int kt2 = 0; kt2 < 4; kt2++){
      floatx4 z = {0.f,0.f,0.f,0.f};
      floatx4 a0 = __builtin_amdgcn_mfma_f32_16x16x32_bf16(kfrag[2*kt2],   qf, z, 0,0,0);
      floatx4 a1 = __builtin_amdgcn_mfma_f32_16x16x32_bf16(kfrag[2*kt2+1], qf, z, 0,0,0);
      float p0[4], p1[4];
      #pragma unroll
      for (int r=0;r<4;r++){
        float m0 = msk[(2*kt2)*16   + quad*4 + r];
        float m1 = msk[(2*kt2+1)*16 + quad*4 + r];
        p0[r] = __expf(fminf(a0[r] + m0, 60.f));
        p1[r] = __expf(fminf(a1[r] + m1, 60.f));
      }
      uint2 u0, u1;
      u0.x = pk2(p0[0], p0[1]); u0.y = pk2(p0[2], p0[3]);
      u1.x = pk2(p1[0], p1[1]); u1.y = pk2(p1[2], p1[3]);
      *(uint2*)&Pl[w][l15][(2*kt2)*16   + quad*4] = u0;
      *(uint2*)&Pl[w][l15][(2*kt2+1)*16 + quad*4] = u1;
    }
    floatx4 o = {0.f,0.f,0.f,0.f};
    #pragma unroll
    for (int ks2=0; ks2<4; ks2++){
      short8 pa = *(const short8*)&Pl[w][l15][ks2*32 + quad*8];
      o = __builtin_amdgcn_mfma_f32_16x16x32_bf16(pa, vfrag[ks2], o, 0,0,0);
    }
    if (l15 < 8){
      #pragma unroll
      for (int r=0;r<4;r++){
        int q = q0 + quad*4 + r;
        pp[(size_t)ks*BSQ*64 + (size_t)(b*SEQ+q)*64 + h*8 + l15] = o[r];
      }
    } else if (l15 == 8){
      #pragma unroll
      for (int r=0;r<4;r++){
        int q = q0 + quad*4 + r;
        ps[(size_t)ks*BSQ*8 + (size_t)(b*SEQ+q)*8 + h] = o[r];
      }
    }
  }
}

// ---- attention combine: sum NSPLIT partials, normalize, emit bf16 ----------
__global__ __launch_bounds__(256) void t12_attn_comb(
    const float* __restrict__ pp, const float* __restrict__ ps,
    short* __restrict__ aout){
  int idx = blockIdx.x*256 + threadIdx.x;   // (bsq, h)
  if (idx >= BSQ*8) return;
  float s = 0.f;
  for (int k=0;k<NSPLIT;k++) s += ps[(size_t)k*BSQ*8 + idx];
  float inv = 1.f/s;
  int bsq = idx >> 3, h = idx & 7;
  size_t base = (size_t)bsq*64 + h*8;
  float o[8] = {};
  for (int k=0;k<NSPLIT;k++){
    const float4* p = (const float4*)(pp + (size_t)k*BSQ*64 + base);
    float4 a = p[0], bq = p[1];
    o[0]+=a.x; o[1]+=a.y; o[2]+=a.z; o[3]+=a.w;
    o[4]+=bq.x; o[5]+=bq.y; o[6]+=bq.z; o[7]+=bq.w;
  }
  short8 r;
  for (int d=0;d<8;d++) r[d] = f2b(o[d]*inv);
  *(short8*)(aout + base) = r;
}

// ---- add + LayerNorm (ddof=1), wave-per-row x4; xb/xc optional addends -----
__global__ __launch_bounds__(256) void t18_addnorm(
                 const float* __restrict__ xa, const float* __restrict__ xb,
                 const float* __restrict__ xc,
                 float* __restrict__ y, short* __restrict__ ybf,
                 float* __restrict__ accum, short* __restrict__ accbf,
                 const float* __restrict__ gamma, const float* __restrict__ beta,
                 int l){
  int w = threadIdx.x >> 6, lane = threadIdx.x & 63;
  int row = blockIdx.x*4 + w;
  size_t base  = (size_t)row*HIDD;
  size_t bbase = (size_t)row*320;
  float v[5];
  float s = 0.f, sq = 0.f;
  #pragma unroll
  for (int t=0;t<5;t++){
    int j = lane + t*64;
    float x = 0.f;
    if (j < HIDD){
      x = xa[base+j];
      if (xb) x += xb[base+j];
      if (xc) x += xc[base+j];
    }
    v[t] = x; s += x; sq += x*x;
  }
  #pragma unroll
  for (int off=32; off; off>>=1){ s += __shfl_down(s,off); sq += __shfl_down(sq,off); }
  s = __shfl(s, 0); sq = __shfl(sq, 0);
  float mu  = s * (1.0f/HIDD);
  float var = (sq - (float)HIDD*mu*mu) * (1.0f/(HIDD-1));
  float rstd = rsqrtf(var + 1e-8f);
  float g = gamma[l], be = beta[l];
  #pragma unroll
  for (int t=0;t<5;t++){
    int j = lane + t*64;
    if (j < HIDD){
      float o = g*(v[t]-mu)*rstd + be;
      if (y) y[base+j] = o;
      if (ybf) ybf[bbase+j] = f2b(o);
      if (accum){
        float a = accum[base+j] + o;
        accum[base+j] = a;
        if (accbf) accbf[bbase+j] = f2b(a);
      }
    } else if (j < 320){
      if (ybf) ybf[bbase+j] = 0;
      if (accbf) accbf[bbase+j] = 0;
    }
  }
}

// ---- colsum stage 1: block = (b, seq-chunk of 64); sum 64 rows ------------
__global__ __launch_bounds__(256) void t13_colsum_part(
    const float* __restrict__ outb, float* __restrict__ part){
  int blk = blockIdx.x;            // 256 blocks: b*8 + c
  int b = blk >> 3, c = blk & 7;
  int tid = threadIdx.x;
  size_t base = (size_t)b*SEQ*HIDD + (size_t)c*64*HIDD;
  int j1 = tid + 256;
  float s0 = 0.f, s1 = 0.f;
  for (int t = 0; t < 64; t++){
    const float* row = outb + base + (size_t)t*HIDD;
    s0 += row[tid];
    if (j1 < HIDD) s1 += row[j1];
  }
  float* dst = part + (size_t)(c*BATCH + b)*HIDD;
  dst[tid] = s0;
  if (j1 < HIDD) dst[j1] = s1;
}

// ---- colsum stage 2: fold 8 partials -> sums[32][300] ----------------------
__global__ void t13_colsum_comb(const float* __restrict__ part,
                                float* __restrict__ sums){
  int idx = blockIdx.x*256 + threadIdx.x;   // b*300 + j
  if (idx >= BATCH*HIDD) return;
  float s = 0.f;
  for (int c = 0; c < 8; c++) s += part[(size_t)c*BATCH*HIDD + idx];
  sums[idx] = s;
}

// ---- classifier GEMM, split-K=4 --------------------------------------------
__global__ __launch_bounds__(256) void t13_cls(
    const float* __restrict__ sums, const float* __restrict__ W,
    float* __restrict__ plog){
  int gid = blockIdx.x*256 + threadIdx.x;
  if (gid >= CLS_KS*BATCH*NCLS) return;
  int c = gid / (BATCH*NCLS);
  int rem = gid - c*(BATCH*NCLS);
  int m = rem / NCLS, n = rem - m*NCLS;
  const float* arow = sums + m*HIDD + c*CLS_KC;
  const float* wcol = W + (size_t)c*CLS_KC*NCLS + n;
  float acc = 0.f;
  #pragma unroll 5
  for (int k = 0; k < CLS_KC; k++)
    acc = fmaf(arow[k], wcol[(size_t)k*NCLS], acc);
  plog[gid] = acc;
}

// ---------------- classifier head: LayerNorm(ddof=1) + softmax -> fp32 -----
__device__ __forceinline__ float t10_bsum(float val, float* red){
  for (int off=32; off; off>>=1) val += __shfl_down(val, off);
  __syncthreads();
  if ((threadIdx.x & 63)==0) red[threadIdx.x>>6] = val;
  __syncthreads();
  return red[0]+red[1]+red[2]+red[3];
}
__device__ __forceinline__ float t10_bmax(float val, float* red){
  for (int off=32; off; off>>=1) val = fmaxf(val, __shfl_down(val, off));
  __syncthreads();
  if ((threadIdx.x & 63)==0) red[threadIdx.x>>6] = val;
  __syncthreads();
  return fmaxf(fmaxf(red[0],red[1]), fmaxf(red[2],red[3]));
}

__global__ __launch_bounds__(256) void t10_final(
                  const float* __restrict__ plog,
                  const float* __restrict__ gf, const float* __restrict__ bff,
                  float* __restrict__ outp){
  __shared__ float red[4];
  int b = blockIdx.x, tid = threadIdx.x;
  size_t base = (size_t)b*NCLS;
  float v[4];
  float s = 0.f, sq = 0.f;
  for (int t=0;t<4;t++){
    int j = tid + t*256;
    float x = 0.f;
    if (j < NCLS){
      for (int c=0;c<CLS_KS;c++) x += plog[(size_t)c*BATCH*NCLS + base + j];
    }
    v[t] = x; s += x; sq += x*x;
  }
  s  = t10_bsum(s, red);
  sq = t10_bsum(sq, red);
  float mu  = s * (1.0f/NCLS);
  float var = (sq - (float)NCLS*mu*mu) * (1.0f/(NCLS-1));
  float rstd = rsqrtf(var + 1e-8f);
  float g = gf[0], be = bff[0];
  float y[4]; float mx = -1e30f;
  for (int t=0;t<4;t++){
    int j = tid + t*256;
    y[t] = g*(v[t]-mu)*rstd + be;
    if (j < NCLS) mx = fmaxf(mx, y[t]);
  }
  mx = t10_bmax(mx, red);
  float p[4]; float es = 0.f;
  for (int t=0;t<4;t++){
    int j = tid + t*256;
    p[t] = (j < NCLS) ? __expf(y[t]-mx) : 0.f;
    es += p[t];
  }
  es = t10_bsum(es, red);
  float inv = 1.0f/es;
  for (int t=0;t<4;t++){
    int j = tid + t*256;
    if (j < NCLS) outp[base+j] = p[t]*inv;
  }
}

// ---------------------------------------------------------------------------
extern "C" void kernel_launch(void* const* d_in, const int* in_sizes, int n_in,
                              void* d_out, int out_size, void* d_ws, size_t ws_size,
                              hipStream_t stream){
  const int*   toks = (const int*)d_in[0];
  const float* emb  = (const float*)d_in[1];
  const float* WQ   = (const float*)d_in[2];
  const float* WK   = (const float*)d_in[3];
  const float* WV   = (const float*)d_in[4];
  const float* WO   = (const float*)d_in[5];
  const float* W1   = (const float*)d_in[6];
  const float* b1   = (const float*)d_in[7];
  const float* W2   = (const float*)d_in[8];
  const float* b2   = (const float*)d_in[9];
  const float* g1   = (const float*)d_in[10];
  const float* be1  = (const float*)d_in[11];
  const float* g2   = (const float*)d_in[12];
  const float* be2  = (const float*)d_in[13];
  const float* Vd   = (const float*)d_in[14];
  const float* gf   = (const float*)d_in[15];
  const float* bff  = (const float*)d_in[16];
  float* outp = (float*)d_out;

  // fp32 buffers
  float* acc    = (float*)d_ws;                         // [BSQ][300]
  float* xn     = acc    + (size_t)BSQ*HIDD;            // [BSQ][300]
  float* outb   = xn     + (size_t)BSQ*HIDD;            // [BSQ][300]
  float* tmp    = outb   + (size_t)BSQ*HIDD;            // [BSQ][300]
  float* qkv    = tmp    + (size_t)BSQ*HIDD;            // slot: >= BSQ*QKVP bf16
  float* sums   = qkv    + (size_t)BSQ*192;             // [32][300]
  float* logits = sums   + BATCH*HIDD;                  // [32][1000] (pad)
  short* qkv_bf = (short*)qkv;                          // [BSQ][QKVP] bf16
  // attention partials alias tmp (dead during attention)
  float* pp     = tmp;
  float* ps     = tmp + (size_t)NSPLIT*BSQ*64;
  // bf16 buffers
  short* acc_bf = (short*)(logits + BATCH*NCLS);        // [BSQ][320]
  short* xn_bf  = acc_bf + (size_t)BSQ*320;             // [BSQ][320]
  short* aat_bf = xn_bf  + (size_t)BSQ*320;             // [BSQ][64]
  short* ff1_bf = aat_bf + (size_t)BSQ*64;              // [BSQ][1280]
  // bf16 weights (row counts padded to 128-tile multiples)
  short* wqkv = ff1_bf + (size_t)BSQ*1280;              // [6][256][320]
  short* wo   = wqkv + (size_t)6*256*320;               // [6][384][64]
  short* w1t  = wo   + (size_t)6*384*64;                // [6][1280][320]
  short* w2t  = w1t  + (size_t)6*1280*320;              // [6][384][1280]
  // classifier-tail fp32 buffers
  float* cspart = (float*)(w2t + (size_t)6*384*1280);   // [8][32][300]
  float* plog   = cspart + (size_t)8*BATCH*HIDD;        // [4][32][1000]

  {
    const float kscale = 0.057735026918962574f;         // 1/sqrt(300) into WK
    int tq = 6*64*320;
    prep_w<<<(tq+255)/256,256,0,stream>>>(WQ, wqkv, 300, 64, 320, 64, 0,   19200, 81920, tq, 1, 1.0f);
    prep_w<<<(tq+255)/256,256,0,stream>>>(WK, wqkv, 300, 64, 320, 64, 64,  19200, 81920, tq, 1, kscale);
    prep_w<<<(tq+255)/256,256,0,stream>>>(WV, wqkv, 300, 64, 320, 64, 128, 19200, 81920, tq, 1, 1.0f);
    prep_w<<<(tq+255)/256,256,0,stream>>>(WQ, wqkv, 300, 0,  320, 64, 192, 19200, 81920, tq, 0, 1.0f);
    int to = 6*384*64;
    prep_w<<<(to+255)/256,256,0,stream>>>(WO, wo, 64, 300, 64, 384, 0, 19200, 24576, to, 0, 1.0f);
    int t1 = 6*1280*320;
    prep_w<<<(t1+255)/256,256,0,stream>>>(W1, w1t, 300, 1200, 320, 1280, 0, 360000, 409600, t1, 0, 1.0f);
    int t2 = 6*384*1280;
    prep_w<<<(t2+255)/256,256,0,stream>>>(W2, w2t, 1200, 300, 1280, 384, 0, 360000, 491520, t2, 0, 1.0f);
  }

  t10_embed<<<(BSQ*320+255)/256, 256, 0, stream>>>(toks, emb, acc, acc_bf);

  for (int l = 0; l < NLAYERS; l++){
    // QKV: [BSQ][320]bf16 @ [256][320] -> qkv_bf [BSQ][256] bf16 (scale in WK)
    mm64<<<256*2,256,0,stream>>>(acc_bf, wqkv + (size_t)l*81920, nullptr, nullptr, qkv_bf,
                                 BSQ, 192, 320, QKVP, 2, 0);
    t18_attn<<<BATCH*NHEAD*NSPLIT, 256, 0, stream>>>(qkv_bf, toks, pp, ps);
    t12_attn_comb<<<(BSQ*8)/256, 256, 0, stream>>>(pp, ps, aat_bf);
    // WO: [BSQ][64]bf16 @ [384][64] -> tmp fp32 [BSQ][300]
    mm_a16<<<256*5,256,0,stream>>>(aat_bf, wo + (size_t)l*24576, nullptr, tmp, nullptr,
                                   BSQ, 300, 64, 0, 5, 0);
    t18_addnorm<<<BSQ/4,256,0,stream>>>(tmp, acc, nullptr, xn, xn_bf, nullptr, nullptr, g1, be1, l);
    // FF1: [BSQ][320]bf16 @ [1280][320] -> ff1 bf16 [BSQ][1280]
    mm128p<<<128*10,256,0,stream>>>(xn_bf, w1t + (size_t)l*409600, b1 + (size_t)l*FFD,
                                    nullptr, ff1_bf, BSQ, 1200, 320, 1280, 10, 1);
    // FF2: BK=64 variant -- half the barrier events, same traffic/order
    mm64b<<<256*3,256,0,stream>>>(ff1_bf, w2t + (size_t)l*491520, b2 + (size_t)l*HIDD,
                                  tmp, BSQ, 300, 1280, 3);
    // l<5: outb write dead; l==5: acc accumulate dead
    t18_addnorm<<<BSQ/4,256,0,stream>>>(tmp, xn, nullptr, (l==NLAYERS-1)?outb:nullptr, nullptr,
                                        (l==NLAYERS-1)?nullptr:acc,
                                        (l==NLAYERS-1)?nullptr:acc_bf, g2, be2, l);
  }

  t13_colsum_part<<<BATCH*8, 256, 0, stream>>>(outb, cspart);
  t13_colsum_comb<<<(BATCH*HIDD+255)/256, 256, 0, stream>>>(cspart, sums);
  t13_cls<<<(CLS_KS*BATCH*NCLS)/256, 256, 0, stream>>>(sums, Vd, plog);
  t10_final<<<BATCH, 256, 0, stream>>>(plog, gf, bff, outp);

  hipStreamCaptureStatus cs = hipStreamCaptureStatusNone;
  hipStreamIsCapturing(stream, &cs);
  if (cs == hipStreamCaptureStatusNone){
    hipError_t e_sync = hipStreamSynchronize(stream);
    float ho[4] = {-1,-1,-1,-1};
    hipMemcpy(ho, d_out, 16, hipMemcpyDeviceToHost);
    fprintf(stderr, "[t22] sync=%s out[0..3]=%g,%g,%g,%g\n",
            hipGetErrorString(e_sync), ho[0], ho[1], ho[2], ho[3]);
    fflush(stderr);
  }
}

// Round 14
// 986.198 us; speedup vs baseline: 1.1373x; 1.0609x over previous
//
#include <hip/hip_runtime.h>
#include <hip/hip_bf16.h>
#include <cstdio>
#include <cstdint>

#define BATCH 32
#define SEQ 512
#define BSQ (BATCH*SEQ)      // 16384
#define HIDD 300
#define HD 64
#define NHEAD 8
#define DHEAD 8
#define NLAYERS 6
#define FFD 1200
#define NCLS 1000
#define NSPLIT 4
#define KCH (SEQ/NSPLIT)     // 128 keys per block
#define QKVP 256             // bf16 qkv row stride (tile-rounded)
#define CLS_KS 4
#define CLS_KC (HIDD/CLS_KS) // 75

typedef short short8 __attribute__((ext_vector_type(8)));
typedef float floatx4 __attribute__((ext_vector_type(4)));

__device__ __forceinline__ short f2b(float v){
  __hip_bfloat16 h = __float2bfloat16(v);
  short s; __builtin_memcpy(&s, &h, 2); return s;
}
__device__ __forceinline__ unsigned pk2(float a, float b){
  return (unsigned)(unsigned short)f2b(a) | ((unsigned)(unsigned short)f2b(b) << 16);
}

// ------- embedding + positional encoding -> acc = 2*emb + pos (fp32 + bf16) -
__global__ void t10_embed(const int* __restrict__ toks,
                          const float* __restrict__ emb,
                          float* __restrict__ acc,
                          short* __restrict__ accbf){
  int idx = blockIdx.x*256 + threadIdx.x;
  if (idx >= BSQ*320) return;
  int row = idx / 320;
  int j   = idx - row*320;
  if (j >= HIDD){ accbf[(size_t)row*320 + j] = 0; return; }
  int t = toks[row];
  float e = emb[(size_t)t*HIDD + j];
  int s = row & (SEQ-1);
  float expo = (float)(j & ~1) * (1.0f/(float)HIDD);
  float ang  = (float)s * expf(-expo * 9.210340371976184f);
  float pe   = (j & 1) ? cosf(ang) : sinf(ang);
  float v = 2.0f*e + pe;
  acc[(size_t)row*HIDD + j] = v;
  accbf[(size_t)row*320 + j] = f2b(v);
}

// ------- weight prep: fp32 [K][N] -> bf16 transposed [Npad][Kpad] -----------
__global__ void prep_w(const float* __restrict__ src, short* __restrict__ dst,
                       int K, int N, int Kpad, int rows, int nbase,
                       int sls, int dls, int total, int perm, float smul){
  int idx = blockIdx.x*256 + threadIdx.x;
  if (idx >= total) return;
  int l   = idx / (rows*Kpad);
  int rem = idx - l*(rows*Kpad);
  int n = rem / Kpad;
  int k = rem - n*Kpad;
  int sc = perm ? ((n & 7)*8 + (n >> 3)) : n;
  float v = (n < N && k < K) ? src[(size_t)l*sls + (size_t)k*N + sc]*smul : 0.f;
  dst[(size_t)l*dls + (size_t)(nbase+n)*Kpad + k] = f2b(v);
}

// ---- bf16 MFMA GEMM, 64x64 tile (WO) ---------------------------------------
__global__ __launch_bounds__(256) void mm_a16(
    const short* __restrict__ A, const short* __restrict__ Wt,
    const float* __restrict__ bias, float* __restrict__ C,
    short* __restrict__ Cb,
    int M, int N, int Kpad, int Npad, int nnb, int relu){
  __shared__ short sA[64][40];
  __shared__ short sB[64][40];
  int wg = blockIdx.x;
  int cpx = gridDim.x >> 3;
  int swz = (wg & 7)*cpx + (wg >> 3);
  int mt = swz / nnb, nt = swz - mt*nnb;
  int m0 = mt*64, n0 = nt*64;
  int tid = threadIdx.x;
  int lane = tid & 63, wv = tid >> 6;
  int wm = (wv & 1)*32, wn = (wv >> 1)*32;
  int l15 = lane & 15, quad = lane >> 4;
  floatx4 acc[2][2] = {};
  int srow = tid >> 2, sko = (tid & 3)*8;
  const short* Arow = A  + (size_t)(m0 + srow)*Kpad + sko;
  const short* Brow = Wt + (size_t)(n0 + srow)*Kpad + sko;
  int nch = Kpad >> 5;
  for (int c = 0; c < nch; c++){
    int k0 = c*32;
    __syncthreads();
    *(short8*)&sA[srow][sko] = *(const short8*)(Arow + k0);
    *(short8*)&sB[srow][sko] = *(const short8*)(Brow + k0);
    __syncthreads();
    short8 af[2], bf[2];
    for (int i=0;i<2;i++)
      af[i] = *(const short8*)&sA[wm + i*16 + l15][quad*8];
    for (int j=0;j<2;j++)
      bf[j] = *(const short8*)&sB[wn + j*16 + l15][quad*8];
    for (int i=0;i<2;i++)
      for (int j=0;j<2;j++)
        acc[i][j] = __builtin_amdgcn_mfma_f32_16x16x32_bf16(af[i], bf[j], acc[i][j], 0,0,0);
  }
  if (Cb){
    for (int j=0;j<2;j++){
      int n = n0 + wn + j*16 + l15;
      float bv = (bias && n < N) ? bias[n] : 0.f;
      for (int i=0;i<2;i++){
        int mbase = m0 + wm + i*16 + quad*4;
        for (int r=0;r<4;r++){
          float cv = acc[i][j][r] + bv;
          if (relu) cv = fmaxf(cv, 0.f);
          Cb[(size_t)(mbase+r)*Npad + n] = (n < N) ? f2b(cv) : (short)0;
        }
      }
    }
  } else {
    for (int j=0;j<2;j++){
      int n = n0 + wn + j*16 + l15;
      if (n >= N) continue;
      float bv = bias ? bias[n] : 0.f;
      for (int i=0;i<2;i++){
        int mbase = m0 + wm + i*16 + quad*4;
        for (int r=0;r<4;r++){
          float cv = acc[i][j][r] + bv;
          if (relu) cv = fmaxf(cv, 0.f);
          C[(size_t)(mbase+r)*N + n] = cv;
        }
      }
    }
  }
}

// ---- bf16 MFMA GEMM, 64x128 tile, BK=64 (QKV / FF2) ------------------------
// Half the barrier events of BK=32; MFMA K-order identical (ascending
// 32-chunks) -> bit-identical output.  [*][72] rows: frag-read bank =
// (36r+c)%32 = (4r+c)%32 -> rows r,r+8 alias = 2-way = free.  LDS 27.6 KB.
__global__ __launch_bounds__(256) void mm64b(
    const short* __restrict__ A, const short* __restrict__ Wt,
    const float* __restrict__ bias, float* __restrict__ C,
    short* __restrict__ Cb,
    int M, int N, int Kpad, int Npad, int nnb, int relu){
  __shared__ short sA[64][72];
  __shared__ short sB[128][72];
  int wg = blockIdx.x;
  int cpx = gridDim.x >> 3;
  int swz = (wg & 7)*cpx + (wg >> 3);
  int mt = swz / nnb, nt = swz - mt*nnb;
  int m0 = mt*64, n0 = nt*128;
  int tid = threadIdx.x;
  int lane = tid & 63, wv = tid >> 6;
  int l15 = lane & 15, quad = lane >> 4;
  int wn = wv*32;
  floatx4 acc[4][2] = {};
  int lr = tid >> 2, lc = (tid & 3)*16;      // 4 threads x 16 cols cover K=64
  const short* Arow  = A  + (size_t)(m0 + lr)*Kpad + lc;
  const short* Brow0 = Wt + (size_t)(n0 + lr)*Kpad + lc;
  const short* Brow1 = Wt + (size_t)(n0 + 64 + lr)*Kpad + lc;
  int nch = Kpad >> 6;
  for (int c = 0; c < nch; c++){
    int k0 = c*64;
    short8 va0 = *(const short8*)(Arow  + k0);
    short8 va1 = *(const short8*)(Arow  + k0 + 8);
    short8 vb0 = *(const short8*)(Brow0 + k0);
    short8 vb1 = *(const short8*)(Brow0 + k0 + 8);
    short8 vc0 = *(const short8*)(Brow1 + k0);
    short8 vc1 = *(const short8*)(Brow1 + k0 + 8);
    __syncthreads();
    *(short8*)&sA[lr][lc]       = va0;
    *(short8*)&sA[lr][lc+8]     = va1;
    *(short8*)&sB[lr][lc]       = vb0;
    *(short8*)&sB[lr][lc+8]     = vb1;
    *(short8*)&sB[64+lr][lc]    = vc0;
    *(short8*)&sB[64+lr][lc+8]  = vc1;
    __syncthreads();
    #pragma unroll
    for (int h = 0; h < 2; h++){
      int ko = h*32 + quad*8;
      short8 af[4], bf[2];
      #pragma unroll
      for (int i=0;i<4;i++)
        af[i] = *(const short8*)&sA[i*16 + l15][ko];
      #pragma unroll
      for (int j=0;j<2;j++)
        bf[j] = *(const short8*)&sB[wn + j*16 + l15][ko];
      #pragma unroll
      for (int i=0;i<4;i++)
        #pragma unroll
        for (int j=0;j<2;j++)
          acc[i][j] = __builtin_amdgcn_mfma_f32_16x16x32_bf16(af[i], bf[j], acc[i][j], 0,0,0);
    }
  }
  if (Cb){
    #pragma unroll
    for (int j=0;j<2;j++){
      int n = n0 + wn + j*16 + l15;
      float bv = (bias && n < N) ? bias[n] : 0.f;
      #pragma unroll
      for (int i=0;i<4;i++){
        int mbase = m0 + i*16 + quad*4;
        #pragma unroll
        for (int r=0;r<4;r++){
          float cv = acc[i][j][r] + bv;
          if (relu) cv = fmaxf(cv, 0.f);
          Cb[(size_t)(mbase+r)*Npad + n] = (n < N) ? f2b(cv) : (short)0;
        }
      }
    }
  } else {
    #pragma unroll
    for (int j=0;j<2;j++){
      int n = n0 + wn + j*16 + l15;
      if (n >= N) continue;
      float bv = bias ? bias[n] : 0.f;
      #pragma unroll
      for (int i=0;i<4;i++){
        int mbase = m0 + i*16 + quad*4;
        #pragma unroll
        for (int r=0;r<4;r++){
          float cv = acc[i][j][r] + bv;
          if (relu) cv = fmaxf(cv, 0.f);
          C[(size_t)(mbase+r)*N + n] = cv;
        }
      }
    }
  }
}

// ---- bf16 MFMA GEMM, 128x128 tile, BK=64 (FF1) -----------------------------
// 32 MFMAs per barrier pair per wave (2x mm128p).  LDS 36.9 KB -> 4 blocks/CU.
__global__ __launch_bounds__(256) void mm128b(
    const short* __restrict__ A, const short* __restrict__ Wt,
    const float* __restrict__ bias, short* __restrict__ Cb,
    int M, int N, int Kpad, int Npad, int nnb, int relu){
  __shared__ short sA[128][72];
  __shared__ short sB[128][72];
  int wg = blockIdx.x;
  int cpx = gridDim.x >> 3;
  int swz = (wg & 7)*cpx + (wg >> 3);
  int mt = swz / nnb, nt = swz - mt*nnb;
  int m0 = mt*128, n0 = nt*128;
  int tid = threadIdx.x;
  int lane = tid & 63, wv = tid >> 6;
  int wm = (wv & 1)*64, wn = (wv >> 1)*64;
  int l15 = lane & 15, quad = lane >> 4;
  floatx4 acc[4][4] = {};
  int lr = tid >> 2, lc = (tid & 3)*16;
  const short* Arow0 = A  + (size_t)(m0 + lr)*Kpad + lc;
  const short* Arow1 = A  + (size_t)(m0 + 64 + lr)*Kpad + lc;
  const short* Brow0 = Wt + (size_t)(n0 + lr)*Kpad + lc;
  const short* Brow1 = Wt + (size_t)(n0 + 64 + lr)*Kpad + lc;
  int nch = Kpad >> 6;
  for (int c = 0; c < nch; c++){
    int k0 = c*64;
    short8 va0 = *(const short8*)(Arow0 + k0);
    short8 va1 = *(const short8*)(Arow0 + k0 + 8);
    short8 va2 = *(const short8*)(Arow1 + k0);
    short8 va3 = *(const short8*)(Arow1 + k0 + 8);
    short8 vb0 = *(const short8*)(Brow0 + k0);
    short8 vb1 = *(const short8*)(Brow0 + k0 + 8);
    short8 vb2 = *(const short8*)(Brow1 + k0);
    short8 vb3 = *(const short8*)(Brow1 + k0 + 8);
    __syncthreads();
    *(short8*)&sA[lr][lc]        = va0;
    *(short8*)&sA[lr][lc+8]      = va1;
    *(short8*)&sA[64+lr][lc]     = va2;
    *(short8*)&sA[64+lr][lc+8]   = va3;
    *(short8*)&sB[lr][lc]        = vb0;
    *(short8*)&sB[lr][lc+8]      = vb1;
    *(short8*)&sB[64+lr][lc]     = vb2;
    *(short8*)&sB[64+lr][lc+8]   = vb3;
    __syncthreads();
    #pragma unroll
    for (int h = 0; h < 2; h++){
      int ko = h*32 + quad*8;
      short8 af[4], bf[4];
      #pragma unroll
      for (int i=0;i<4;i++)
        af[i] = *(const short8*)&sA[wm + i*16 + l15][ko];
      #pragma unroll
      for (int j=0;j<4;j++)
        bf[j] = *(const short8*)&sB[wn + j*16 + l15][ko];
      #pragma unroll
      for (int i=0;i<4;i++)
        #pragma unroll
        for (int j=0;j<4;j++)
          acc[i][j] = __builtin_amdgcn_mfma_f32_16x16x32_bf16(af[i], bf[j], acc[i][j], 0,0,0);
    }
  }
  #pragma unroll
  for (int j=0;j<4;j++){
    int n = n0 + wn + j*16 + l15;
    float bv = (bias && n < N) ? bias[n] : 0.f;
    #pragma unroll
    for (int i=0;i<4;i++){
      int mbase = m0 + wm + i*16 + quad*4;
      #pragma unroll
      for (int r=0;r<4;r++){
        float cv = acc[i][j][r] + bv;
        if (relu) cv = fmaxf(cv, 0.f);
        Cb[(size_t)(mbase+r)*Npad + n] = (n < N) ? f2b(cv) : (short)0;
      }
    }
  }
}

// ---- MFMA attention partial: qkv bf16 [BSQ][QKVP]; scale pre-folded --------
__global__ __launch_bounds__(256) void t18_attn(
    const short* __restrict__ qkvb, const int* __restrict__ toks,
    float* __restrict__ pp, float* __restrict__ ps){
  __shared__ short vb16[KCH][16];
  __shared__ float msk[KCH];
  __shared__ short Pl[4][16][136];
  int blk = blockIdx.x;
  int ks = blk & (NSPLIT-1);
  int bh = blk >> 2;
  int b = bh >> 3, h = bh & 7;
  int tid = threadIdx.x;
  int lane = tid & 63, w = tid >> 6;
  int quad = lane >> 4, l15 = lane & 15;
  int kbase = ks*KCH;
  if (tid < KCH){
    *(short8*)&vb16[tid][0] =
      *(const short8*)(qkvb + (size_t)(b*SEQ + kbase + tid)*QKVP + 128 + h*8);
  } else {
    int r = tid - KCH;
    msk[r] = (toks[b*SEQ + kbase + r]==0) ? -1e9f : 0.f;
  }
  __syncthreads();

  short8 kfrag[8];
  #pragma unroll
  for (int kt=0;kt<8;kt++){
    short8 f;
    #pragma unroll
    for (int j=0;j<8;j++) f[j] = 0;
    if (quad == 0)
      f = *(const short8*)(qkvb + (size_t)(b*SEQ + kbase + kt*16 + l15)*QKVP + 64 + h*8);
    kfrag[kt] = f;
  }
  short8 vfrag[4];
  #pragma unroll
  for (int ks2=0;ks2<4;ks2++){
    short8 f;
    #pragma unroll
    for (int j=0;j<8;j++) f[j] = 0;
    if (l15 < 8){
      #pragma unroll
      for (int j=0;j<8;j++) f[j] = vb16[ks2*32 + quad*8 + j][l15];
    } else if (l15 == 8){
      #pragma unroll
      for (int j=0;j<8;j++) f[j] = (short)0x3F80;
    }
    vfrag[ks2] = f;
  }

  for (int t = 0; t < 8; t++){
    int q0 = w*128 + t*16;
    short8 qf;
    #pragma unroll
    for (int j=0;j<8;j++) qf[j] = 0;
    if (quad == 0)
      qf = *(const short8*)(qkvb + (size_t)(b*SEQ + q0 + l15)*QKVP + h*8);
    #pragma unroll
    for (int kt2 = 0; kt2 < 4; kt2++){
      floatx4 z = {0.f,0.f,0.f,0.f};
      floatx4 a0 = __builtin_amdgcn_mfma_f32_16x16x32_bf16(kfrag[2*kt2],   qf, z, 0,0,0);
      floatx4 a1 = __builtin_amdgcn_mfma_f32_16x16x32_bf16(kfrag[2*kt2+1], qf, z, 0,0,0);
      float p0[4], p1[4];
      #pragma unroll
      for (int r=0;r<4;r++){
        float m0 = msk[(2*kt2)*16   + quad*4 + r];
        float m1 = msk[(2*kt2+1)*16 + quad*4 + r];
        p0[r] = __expf(fminf(a0[r] + m0, 60.f));
        p1[r] = __expf(fminf(a1[r] + m1, 60.f));
      }
      uint2 u0, u1;
      u0.x = pk2(p0[0], p0[1]); u0.y = pk2(p0[2], p0[3]);
      u1.x = pk2(p1[0], p1[1]); u1.y = pk2(p1[2], p1[3]);
      *(uint2*)&Pl[w][l15][(2*kt2)*16   + quad*4] = u0;
      *(uint2*)&Pl[w][l15][(2*kt2+1)*16 + quad*4] = u1;
    }
    floatx4 o = {0.f,0.f,0.f,0.f};
    #pragma unroll
    for (int ks2=0; ks2<4; ks2++){
      short8 pa = *(const short8*)&Pl[w][l15][ks2*32 + quad*8];
      o = __builtin_amdgcn_mfma_f32_16x16x32_bf16(pa, vfrag[ks2], o, 0,0,0);
    }
    if (l15 < 8){
      #pragma unroll
      for (int r=0;r<4;r++){
        int q = q0 + quad*4 + r;
        pp[(size_t)ks*BSQ*64 + (size_t)(b*SEQ+q)*64 + h*8 + l15] = o[r];
      }
    } else if (l15 == 8){
      #pragma unroll
      for (int r=0;r<4;r++){
        int q = q0 + quad*4 + r;
        ps[(size_t)ks*BSQ*8 + (size_t)(b*SEQ+q)*8 + h] = o[r];
      }
    }
  }
}

// ---- attention combine: sum NSPLIT partials, normalize, emit bf16 ----------
__global__ __launch_bounds__(256) void t12_attn_comb(
    const float* __restrict__ pp, const float* __restrict__ ps,
    short* __restrict__ aout){
  int idx = blockIdx.x*256 + threadIdx.x;   // (bsq, h)
  if (idx >= BSQ*8) return;
  float s = 0.f;
  for (int k=0;k<NSPLIT;k++) s += ps[(size_t)k*BSQ*8 + idx];
  float inv = 1.f/s;
  int bsq = idx >> 3, h = idx & 7;
  size_t base = (size_t)bsq*64 + h*8;
  float o[8] = {};
  for (int k=0;k<NSPLIT;k++){
    const float4* p = (const float4*)(pp + (size_t)k*BSQ*64 + base);
    float4 a = p[0], bq = p[1];
    o[0]+=a.x; o[1]+=a.y; o[2]+=a.z; o[3]+=a.w;
    o[4]+=bq.x; o[5]+=bq.y; o[6]+=bq.z; o[7]+=bq.w;
  }
  short8 r;
  for (int d=0;d<8;d++) r[d] = f2b(o[d]*inv);
  *(short8*)(aout + base) = r;
}

// ---- add + LayerNorm (ddof=1), wave-per-row x4; xb/xc optional addends -----
__global__ __launch_bounds__(256) void t18_addnorm(
                 const float* __restrict__ xa, const float* __restrict__ xb,
                 const float* __restrict__ xc,
                 float* __restrict__ y, short* __restrict__ ybf,
                 float* __restrict__ accum, short* __restrict__ accbf,
                 const float* __restrict__ gamma, const float* __restrict__ beta,
                 int l){
  int w = threadIdx.x >> 6, lane = threadIdx.x & 63;
  int row = blockIdx.x*4 + w;
  size_t base  = (size_t)row*HIDD;
  size_t bbase = (size_t)row*320;
  float v[5];
  float s = 0.f, sq = 0.f;
  #pragma unroll
  for (int t=0;t<5;t++){
    int j = lane + t*64;
    float x = 0.f;
    if (j < HIDD){
      x = xa[base+j];
      if (xb) x += xb[base+j];
      if (xc) x += xc[base+j];
    }
    v[t] = x; s += x; sq += x*x;
  }
  #pragma unroll
  for (int off=32; off; off>>=1){ s += __shfl_down(s,off); sq += __shfl_down(sq,off); }
  s = __shfl(s, 0); sq = __shfl(sq, 0);
  float mu  = s * (1.0f/HIDD);
  float var = (sq - (float)HIDD*mu*mu) * (1.0f/(HIDD-1));
  float rstd = rsqrtf(var + 1e-8f);
  float g = gamma[l], be = beta[l];
  #pragma unroll
  for (int t=0;t<5;t++){
    int j = lane + t*64;
    if (j < HIDD){
      float o = g*(v[t]-mu)*rstd + be;
      if (y) y[base+j] = o;
      if (ybf) ybf[bbase+j] = f2b(o);
      if (accum){
        float a = accum[base+j] + o;
        accum[base+j] = a;
        if (accbf) accbf[bbase+j] = f2b(a);
      }
    } else if (j < 320){
      if (ybf) ybf[bbase+j] = 0;
      if (accbf) accbf[bbase+j] = 0;
    }
  }
}

// ---- colsum stage 1: block = (b, seq-chunk of 64); sum 64 rows ------------
__global__ __launch_bounds__(256) void t13_colsum_part(
    const float* __restrict__ outb, float* __restrict__ part){
  int blk = blockIdx.x;            // 256 blocks: b*8 + c
  int b = blk >> 3, c = blk & 7;
  int tid = threadIdx.x;
  size_t base = (size_t)b*SEQ*HIDD + (size_t)c*64*HIDD;
  int j1 = tid + 256;
  float s0 = 0.f, s1 = 0.f;
  for (int t = 0; t < 64; t++){
    const float* row = outb + base + (size_t)t*HIDD;
    s0 += row[tid];
    if (j1 < HIDD) s1 += row[j1];
  }
  float* dst = part + (size_t)(c*BATCH + b)*HIDD;
  dst[tid] = s0;
  if (j1 < HIDD) dst[j1] = s1;
}

// ---- colsum stage 2: fold 8 partials -> sums[32][300] ----------------------
__global__ void t13_colsum_comb(const float* __restrict__ part,
                                float* __restrict__ sums){
  int idx = blockIdx.x*256 + threadIdx.x;   // b*300 + j
  if (idx >= BATCH*HIDD) return;
  float s = 0.f;
  for (int c = 0; c < 8; c++) s += part[(size_t)c*BATCH*HIDD + idx];
  sums[idx] = s;
}

// ---- classifier GEMM, split-K=4 --------------------------------------------
__global__ __launch_bounds__(256) void t13_cls(
    const float* __restrict__ sums, const float* __restrict__ W,
    float* __restrict__ plog){
  int gid = blockIdx.x*256 + threadIdx.x;
  if (gid >= CLS_KS*BATCH*NCLS) return;
  int c = gid / (BATCH*NCLS);
  int rem = gid - c*(BATCH*NCLS);
  int m = rem / NCLS, n = rem - m*NCLS;
  const float* arow = sums + m*HIDD + c*CLS_KC;
  const float* wcol = W + (size_t)c*CLS_KC*NCLS + n;
  float acc = 0.f;
  #pragma unroll 5
  for (int k = 0; k < CLS_KC; k++)
    acc = fmaf(arow[k], wcol[(size_t)k*NCLS], acc);
  plog[gid] = acc;
}

// ---------------- classifier head: LayerNorm(ddof=1) + softmax -> fp32 -----
__device__ __forceinline__ float t10_bsum(float val, float* red){
  for (int off=32; off; off>>=1) val += __shfl_down(val, off);
  __syncthreads();
  if ((threadIdx.x & 63)==0) red[threadIdx.x>>6] = val;
  __syncthreads();
  return red[0]+red[1]+red[2]+red[3];
}
__device__ __forceinline__ float t10_bmax(float val, float* red){
  for (int off=32; off; off>>=1) val = fmaxf(val, __shfl_down(val, off));
  __syncthreads();
  if ((threadIdx.x & 63)==0) red[threadIdx.x>>6] = val;
  __syncthreads();
  return fmaxf(fmaxf(red[0],red[1]), fmaxf(red[2],red[3]));
}

__global__ __launch_bounds__(256) void t10_final(
                  const float* __restrict__ plog,
                  const float* __restrict__ gf, const float* __restrict__ bff,
                  float* __restrict__ outp){
  __shared__ float red[4];
  int b = blockIdx.x, tid = threadIdx.x;
  size_t base = (size_t)b*NCLS;
  float v[4];
  float s = 0.f, sq = 0.f;
  for (int t=0;t<4;t++){
    int j = tid + t*256;
    float x = 0.f;
    if (j < NCLS){
      for (int c=0;c<CLS_KS;c++) x += plog[(size_t)c*BATCH*NCLS + base + j];
    }
    v[t] = x; s += x; sq += x*x;
  }
  s  = t10_bsum(s, red);
  sq = t10_bsum(sq, red);
  float mu  = s * (1.0f/NCLS);
  float var = (sq - (float)NCLS*mu*mu) * (1.0f/(NCLS-1));
  float rstd = rsqrtf(var + 1e-8f);
  float g = gf[0], be = bff[0];
  float y[4]; float mx = -1e30f;
  for (int t=0;t<4;t++){
    int j = tid + t*256;
    y[t] = g*(v[t]-mu)*rstd + be;
    if (j < NCLS) mx = fmaxf(mx, y[t]);
  }
  mx = t10_bmax(mx, red);
  float p[4]; float es = 0.f;
  for (int t=0;t<4;t++){
    int j = tid + t*256;
    p[t] = (j < NCLS) ? __expf(y[t]-mx) : 0.f;
    es += p[t];
  }
  es = t10_bsum(es, red);
  float inv = 1.0f/es;
  for (int t=0;t<4;t++){
    int j = tid + t*256;
    if (j < NCLS) outp[base+j] = p[t]*inv;
  }
}

// ---------------------------------------------------------------------------
extern "C" void kernel_launch(void* const* d_in, const int* in_sizes, int n_in,
                              void* d_out, int out_size, void* d_ws, size_t ws_size,
                              hipStream_t stream){
  const int*   toks = (const int*)d_in[0];
  const float* emb  = (const float*)d_in[1];
  const float* WQ   = (const float*)d_in[2];
  const float* WK   = (const float*)d_in[3];
  const float* WV   = (const float*)d_in[4];
  const float* WO   = (const float*)d_in[5];
  const float* W1   = (const float*)d_in[6];
  const float* b1   = (const float*)d_in[7];
  const float* W2   = (const float*)d_in[8];
  const float* b2   = (const float*)d_in[9];
  const float* g1   = (const float*)d_in[10];
  const float* be1  = (const float*)d_in[11];
  const float* g2   = (const float*)d_in[12];
  const float* be2  = (const float*)d_in[13];
  const float* Vd   = (const float*)d_in[14];
  const float* gf   = (const float*)d_in[15];
  const float* bff  = (const float*)d_in[16];
  float* outp = (float*)d_out;

  // fp32 buffers
  float* acc    = (float*)d_ws;                         // [BSQ][300]
  float* xn     = acc    + (size_t)BSQ*HIDD;            // [BSQ][300]
  float* outb   = xn     + (size_t)BSQ*HIDD;            // [BSQ][300]
  float* tmp    = outb   + (size_t)BSQ*HIDD;            // [BSQ][300]
  float* qkv    = tmp    + (size_t)BSQ*HIDD;            // slot: >= BSQ*QKVP bf16
  float* sums   = qkv    + (size_t)BSQ*192;             // [32][300]
  float* logits = sums   + BATCH*HIDD;                  // [32][1000] (pad)
  short* qkv_bf = (short*)qkv;                          // [BSQ][QKVP] bf16
  // attention partials alias tmp (dead during attention)
  float* pp     = tmp;
  float* ps     = tmp + (size_t)NSPLIT*BSQ*64;
  // bf16 buffers
  short* acc_bf = (short*)(logits + BATCH*NCLS);        // [BSQ][320]
  short* xn_bf  = acc_bf + (size_t)BSQ*320;             // [BSQ][320]
  short* aat_bf = xn_bf  + (size_t)BSQ*320;             // [BSQ][64]
  short* ff1_bf = aat_bf + (size_t)BSQ*64;              // [BSQ][1280]
  // bf16 weights (row counts padded to 128-tile multiples)
  short* wqkv = ff1_bf + (size_t)BSQ*1280;              // [6][256][320]
  short* wo   = wqkv + (size_t)6*256*320;               // [6][384][64]
  short* w1t  = wo   + (size_t)6*384*64;                // [6][1280][320]
  short* w2t  = w1t  + (size_t)6*1280*320;              // [6][384][1280]
  // classifier-tail fp32 buffers
  float* cspart = (float*)(w2t + (size_t)6*384*1280);   // [8][32][300]
  float* plog   = cspart + (size_t)8*BATCH*HIDD;        // [4][32][1000]

  {
    const float kscale = 0.057735026918962574f;         // 1/sqrt(300) into WK
    int tq = 6*64*320;
    prep_w<<<(tq+255)/256,256,0,stream>>>(WQ, wqkv, 300, 64, 320, 64, 0,   19200, 81920, tq, 1, 1.0f);
    prep_w<<<(tq+255)/256,256,0,stream>>>(WK, wqkv, 300, 64, 320, 64, 64,  19200, 81920, tq, 1, kscale);
    prep_w<<<(tq+255)/256,256,0,stream>>>(WV, wqkv, 300, 64, 320, 64, 128, 19200, 81920, tq, 1, 1.0f);
    prep_w<<<(tq+255)/256,256,0,stream>>>(WQ, wqkv, 300, 0,  320, 64, 192, 19200, 81920, tq, 0, 1.0f);
    int to = 6*384*64;
    prep_w<<<(to+255)/256,256,0,stream>>>(WO, wo, 64, 300, 64, 384, 0, 19200, 24576, to, 0, 1.0f);
    int t1 = 6*1280*320;
    prep_w<<<(t1+255)/256,256,0,stream>>>(W1, w1t, 300, 1200, 320, 1280, 0, 360000, 409600, t1, 0, 1.0f);
    int t2 = 6*384*1280;
    prep_w<<<(t2+255)/256,256,0,stream>>>(W2, w2t, 1200, 300, 1280, 384, 0, 360000, 491520, t2, 0, 1.0f);
  }

  t10_embed<<<(BSQ*320+255)/256, 256, 0, stream>>>(toks, emb, acc, acc_bf);

  for (int l = 0; l < NLAYERS; l++){
    // QKV: BK=64 -> qkv_bf [BSQ][256] bf16 (scale in WK)
    mm64b<<<256*2,256,0,stream>>>(acc_bf, wqkv + (size_t)l*81920, nullptr, nullptr, qkv_bf,
                                  BSQ, 192, 320, QKVP, 2, 0);
    t18_attn<<<BATCH*NHEAD*NSPLIT, 256, 0, stream>>>(qkv_bf, toks, pp, ps);
    t12_attn_comb<<<(BSQ*8)/256, 256, 0, stream>>>(pp, ps, aat_bf);
    // WO: [BSQ][64]bf16 @ [384][64] -> tmp fp32 [BSQ][300]
    mm_a16<<<256*5,256,0,stream>>>(aat_bf, wo + (size_t)l*24576, nullptr, tmp, nullptr,
                                   BSQ, 300, 64, 0, 5, 0);
    t18_addnorm<<<BSQ/4,256,0,stream>>>(tmp, acc, nullptr, xn, xn_bf, nullptr, nullptr, g1, be1, l);
    // FF1: BK=64, 128x128 -> ff1 bf16 [BSQ][1280] (bias+relu)
    mm128b<<<128*10,256,0,stream>>>(xn_bf, w1t + (size_t)l*409600, b1 + (size_t)l*FFD,
                                    ff1_bf, BSQ, 1200, 320, 1280, 10, 1);
    // FF2: BK=64 -> tmp fp32 [BSQ][300] (bias)
    mm64b<<<256*3,256,0,stream>>>(ff1_bf, w2t + (size_t)l*491520, b2 + (size_t)l*HIDD,
                                  tmp, nullptr, BSQ, 300, 1280, 0, 3, 0);
    // l<5: outb write dead; l==5: acc accumulate dead
    t18_addnorm<<<BSQ/4,256,0,stream>>>(tmp, xn, nullptr, (l==NLAYERS-1)?outb:nullptr, nullptr,
                                        (l==NLAYERS-1)?nullptr:acc,
                                        (l==NLAYERS-1)?nullptr:acc_bf, g2, be2, l);
  }

  t13_colsum_part<<<BATCH*8, 256, 0, stream>>>(outb, cspart);
  t13_colsum_comb<<<(BATCH*HIDD+255)/256, 256, 0, stream>>>(cspart, sums);
  t13_cls<<<(CLS_KS*BATCH*NCLS)/256, 256, 0, stream>>>(sums, Vd, plog);
  t10_final<<<BATCH, 256, 0, stream>>>(plog, gf, bff, outp);

  hipStreamCaptureStatus cs = hipStreamCaptureStatusNone;
  hipStreamIsCapturing(stream, &cs);
  if (cs == hipStreamCaptureStatusNone){
    hipError_t e_sync = hipStreamSynchronize(stream);
    float ho[4] = {-1,-1,-1,-1};
    hipMemcpy(ho, d_out, 16, hipMemcpyDeviceToHost);
    fprintf(stderr, "[t23] sync=%s out[0..3]=%g,%g,%g,%g\n",
            hipGetErrorString(e_sync), ho[0], ho[1], ho[2], ho[3]);
    fflush(stderr);
  }
}